// Round 4
// baseline (2453.613 us; speedup 1.0000x reference)
//
#include <hip/hip_runtime.h>

#define SCAN_CHUNK 1024

__device__ inline float4 f4_xor_add(float4 v, int mask) {
    v.x += __shfl_xor(v.x, mask);
    v.y += __shfl_xor(v.y, mask);
    v.z += __shfl_xor(v.z, mask);
    v.w += __shfl_xor(v.w, mask);
    return v;
}

// ---------------------------------------------------------------------------
// CSR build
// ---------------------------------------------------------------------------
__global__ void hist_kernel(const int* __restrict__ dst, int* __restrict__ deg, int E)
{
    int e = blockIdx.x * blockDim.x + threadIdx.x;
    if (e < E) atomicAdd(&deg[dst[e]], 1);
}

__global__ __launch_bounds__(256) void scanA_kernel(const int* __restrict__ deg,
                                                    int* __restrict__ part, int N)
{
    __shared__ int red[256];
    int b = blockIdx.x, t = threadIdx.x;
    int base = b * SCAN_CHUNK;
    int s = 0;
    for (int i = t; i < SCAN_CHUNK; i += 256) {
        int idx = base + i;
        s += (idx < N) ? deg[idx] : 0;
    }
    red[t] = s;
    __syncthreads();
    for (int o = 128; o > 0; o >>= 1) {
        if (t < o) red[t] += red[t + o];
        __syncthreads();
    }
    if (t == 0) part[b] = red[0];
}

__global__ void scanB_kernel(int* __restrict__ part, int* __restrict__ offN, int NCH)
{
    int lane = threadIdx.x;
    int orig = (lane < NCH) ? part[lane] : 0;
    int v = orig;
    for (int s = 1; s < 64; s <<= 1) {
        int t = __shfl_up(v, s);
        if (lane >= s) v += t;
    }
    if (lane < NCH) part[lane] = v - orig;
    if (lane == NCH - 1) *offN = v;
}

__global__ __launch_bounds__(SCAN_CHUNK) void scanC_kernel(const int* __restrict__ deg,
                                                           const int* __restrict__ part,
                                                           int* __restrict__ off,
                                                           int* __restrict__ cursor, int N)
{
    __shared__ int buf[SCAN_CHUNK];
    int b = blockIdx.x, t = threadIdx.x;
    int idx = b * SCAN_CHUNK + t;
    int v = (idx < N) ? deg[idx] : 0;
    buf[t] = v;
    __syncthreads();
    for (int s = 1; s < SCAN_CHUNK; s <<= 1) {
        int tmp = (t >= s) ? buf[t - s] : 0;
        __syncthreads();
        buf[t] += tmp;
        __syncthreads();
    }
    int excl = buf[t] - v + part[b];
    if (idx < N) { off[idx] = excl; cursor[idx] = excl; }
}

__global__ void fill_kernel(const int* __restrict__ src, const int* __restrict__ dst,
                            int* __restrict__ cursor, int2* __restrict__ elist, int E)
{
    int e = blockIdx.x * blockDim.x + threadIdx.x;
    if (e >= E) return;
    int d = dst[e];
    int p = atomicAdd(&cursor[d], 1);
    elist[p] = make_int2(src[e], e);
}

// ---------------------------------------------------------------------------
// Layer-1 aggregate: one wave per node; float4 row gathers.
// x: 16-lane groups, 4 rows in flight. ea: 8-lane groups, 8 rows in flight.
// ---------------------------------------------------------------------------
__global__ __launch_bounds__(256) void agg1_kernel(const float4* __restrict__ x4,
                                                   const float4* __restrict__ ea4,
                                                   const int2* __restrict__ elist,
                                                   const int* __restrict__ off,
                                                   float4* __restrict__ S1v,
                                                   float4* __restrict__ EAv, int N)
{
    int wv = (blockIdx.x * blockDim.x + threadIdx.x) >> 6;
    int lane = threadIdx.x & 63;
    if (wv >= N) return;
    int beg = off[wv], end = off[wv + 1];

    // x part: 64 feats = 16 float4
    int g4 = lane >> 4, s4 = lane & 15;
    float4 ax = make_float4(0.f, 0.f, 0.f, 0.f);
    for (int i = beg + g4; i < end; i += 4) {
        int row = elist[i].x;
        float4 v = x4[(size_t)row * 16 + s4];
        ax.x += v.x; ax.y += v.y; ax.z += v.z; ax.w += v.w;
    }
    ax = f4_xor_add(ax, 16);
    ax = f4_xor_add(ax, 32);
    if (lane < 16) S1v[(size_t)wv * 16 + s4] = ax;

    // ea part: 32 feats = 8 float4
    int g8 = lane >> 3, s8 = lane & 7;
    float4 ae = make_float4(0.f, 0.f, 0.f, 0.f);
    for (int i = beg + g8; i < end; i += 8) {
        int eid = elist[i].y;
        float4 v = ea4[(size_t)eid * 8 + s8];
        ae.x += v.x; ae.y += v.y; ae.z += v.z; ae.w += v.w;
    }
    ae = f4_xor_add(ae, 8);
    ae = f4_xor_add(ae, 16);
    ae = f4_xor_add(ae, 32);
    if (lane < 8) EAv[(size_t)wv * 8 + s8] = ae;
}

// ---------------------------------------------------------------------------
// Layer-2 aggregate: one wave per node; g2 rows (64f) via 16-lane float4 groups.
// ---------------------------------------------------------------------------
__global__ __launch_bounds__(256) void agg2_kernel(const float4* __restrict__ g24,
                                                   const int2* __restrict__ elist,
                                                   const int* __restrict__ off,
                                                   float4* __restrict__ S2gv, int N)
{
    int wv = (blockIdx.x * blockDim.x + threadIdx.x) >> 6;
    int lane = threadIdx.x & 63;
    if (wv >= N) return;
    int beg = off[wv], end = off[wv + 1];

    int g4 = lane >> 4, s4 = lane & 15;
    float4 ag = make_float4(0.f, 0.f, 0.f, 0.f);
    for (int i = beg + g4; i < end; i += 4) {
        int row = elist[i].x;
        float4 v = g24[(size_t)row * 16 + s4];
        ag.x += v.x; ag.y += v.y; ag.z += v.z; ag.w += v.w;
    }
    ag = f4_xor_add(ag, 16);
    ag = f4_xor_add(ag, 32);
    if (lane < 16) S2gv[(size_t)wv * 16 + s4] = ag;
}

// ---------------------------------------------------------------------------
// Layer-1 node kernel + fused g2 = h1 @ Wmsg2[0:128].
// 512 threads: j = t&127 (out col), g = t>>7 (0..3) -> nodes g*4..g*4+3, acc[4].
// ---------------------------------------------------------------------------
#define NPB1 16
__global__ __launch_bounds__(512) void node1_kernel(
    const float* __restrict__ x,
    const float* __restrict__ S1,
    const float* __restrict__ EA,
    const int*   __restrict__ deg,
    const float* __restrict__ Wmsg,   // [96][128]
    const float* __restrict__ bmsg,   // [128]
    const float* __restrict__ Wapp,   // [192][128]
    const float* __restrict__ bapp,   // [128]
    const float* __restrict__ Wm2h,   // Wmsg2 rows 0..127 -> [128][64]
    float* __restrict__ h1,
    float* __restrict__ g2,
    int N)
{
    __shared__ __align__(16) float sF[NPB1][96];    // [S1 | EA]
    __shared__ __align__(16) float sX[NPB1][64];
    __shared__ __align__(16) float sAgg[NPB1][128];
    __shared__ __align__(16) float sH[NPB1][128];
    __shared__ float sCnt[NPB1];

    int t = threadIdx.x;              // 0..511
    int j = t & 127;                  // output column
    int g = t >> 7;                   // node group 0..3
    int base = blockIdx.x * NPB1;

    for (int q = t; q < NPB1 * 64; q += 512) {
        int n = q >> 6, k = q & 63;
        int v = base + n;
        sF[n][k] = (v < N) ? S1[(size_t)v * 64 + k] : 0.f;
        sX[n][k] = (v < N) ? x[(size_t)v * 64 + k] : 0.f;
    }
    if (t < NPB1 * 32) {
        int n = t >> 5, k = t & 31;
        int v = base + n;
        sF[n][64 + k] = (v < N) ? EA[(size_t)v * 32 + k] : 0.f;
    }
    if (t < NPB1) {
        int v = base + t;
        sCnt[t] = (v < N) ? (float)deg[v] : 0.f;
    }
    __syncthreads();

    float acc[4];
#pragma unroll
    for (int n = 0; n < 4; n++) acc[n] = 0.f;

    for (int k = 0; k < 96; k += 4) {
        float w0 = Wmsg[(k + 0) * 128 + j];
        float w1 = Wmsg[(k + 1) * 128 + j];
        float w2 = Wmsg[(k + 2) * 128 + j];
        float w3 = Wmsg[(k + 3) * 128 + j];
#pragma unroll
        for (int n = 0; n < 4; n++) {
            float4 f = *(const float4*)&sF[g * 4 + n][k];
            acc[n] += f.x * w0 + f.y * w1 + f.z * w2 + f.w * w3;
        }
    }
    float bm = bmsg[j];
#pragma unroll
    for (int n = 0; n < 4; n++) {
        float c = sCnt[g * 4 + n];
        sAgg[g * 4 + n][j] = (acc[n] + c * bm) / fmaxf(c, 1.0f);
    }
    __syncthreads();

#pragma unroll
    for (int n = 0; n < 4; n++) acc[n] = 0.f;
    for (int k = 0; k < 64; k += 4) {
        float w0 = Wapp[(k + 0) * 128 + j];
        float w1 = Wapp[(k + 1) * 128 + j];
        float w2 = Wapp[(k + 2) * 128 + j];
        float w3 = Wapp[(k + 3) * 128 + j];
#pragma unroll
        for (int n = 0; n < 4; n++) {
            float4 f = *(const float4*)&sX[g * 4 + n][k];
            acc[n] += f.x * w0 + f.y * w1 + f.z * w2 + f.w * w3;
        }
    }
    for (int k = 0; k < 128; k += 4) {
        float w0 = Wapp[(64 + k + 0) * 128 + j];
        float w1 = Wapp[(64 + k + 1) * 128 + j];
        float w2 = Wapp[(64 + k + 2) * 128 + j];
        float w3 = Wapp[(64 + k + 3) * 128 + j];
#pragma unroll
        for (int n = 0; n < 4; n++) {
            float4 f = *(const float4*)&sAgg[g * 4 + n][k];
            acc[n] += f.x * w0 + f.y * w1 + f.z * w2 + f.w * w3;
        }
    }
    float ba = bapp[j];
#pragma unroll
    for (int n = 0; n < 4; n++) {
        int v = base + g * 4 + n;
        float hv = fmaxf(acc[n] + ba, 0.f);
        sH[g * 4 + n][j] = hv;
        if (v < N) h1[(size_t)v * 128 + j] = hv;
    }
    __syncthreads();

    // g2 = sH @ Wm2h (128 -> 64): col = t&63, q = t>>6 (0..7) -> 2 nodes each
    int col = t & 63;
    int q = t >> 6;
    float a0 = 0.f, a1 = 0.f;
    for (int k = 0; k < 128; k += 4) {
        float w0 = Wm2h[(k + 0) * 64 + col];
        float w1 = Wm2h[(k + 1) * 64 + col];
        float w2 = Wm2h[(k + 2) * 64 + col];
        float w3 = Wm2h[(k + 3) * 64 + col];
        float4 f0 = *(const float4*)&sH[q * 2 + 0][k];
        float4 f1 = *(const float4*)&sH[q * 2 + 1][k];
        a0 += f0.x * w0 + f0.y * w1 + f0.z * w2 + f0.w * w3;
        a1 += f1.x * w0 + f1.y * w1 + f1.z * w2 + f1.w * w3;
    }
    int v0 = base + q * 2 + 0;
    int v1 = base + q * 2 + 1;
    if (v0 < N) g2[(size_t)v0 * 64 + col] = a0;
    if (v1 < N) g2[(size_t)v1 * 64 + col] = a1;
}

// ---------------------------------------------------------------------------
// Layer-2 node kernel. 256 threads: j = t&63, w = t>>6 -> nodes w*4..w*4+3.
// ---------------------------------------------------------------------------
#define NPB2 16
__global__ __launch_bounds__(256) void node2_kernel(
    const float* __restrict__ h1,
    const float* __restrict__ S2g,
    const float* __restrict__ EA,
    const int*   __restrict__ deg,
    const float* __restrict__ Wme,    // Wmsg2 rows 128..159 -> [32][64]
    const float* __restrict__ bmsg,   // [64]
    const float* __restrict__ Wapp,   // [192][64]
    const float* __restrict__ bapp,   // [64]
    float* __restrict__ out,
    int N)
{
    __shared__ __align__(16) float sEA[NPB2][32];
    __shared__ __align__(16) float sH[NPB2][128];
    __shared__ __align__(16) float sAgg[NPB2][64];
    __shared__ float sCnt[NPB2];

    int t = threadIdx.x;              // 0..255
    int j = t & 63;                   // output column
    int w = t >> 6;                   // node group 0..3
    int base = blockIdx.x * NPB2;

    for (int q = t; q < NPB2 * 128; q += 256) {
        int n = q >> 7, k = q & 127;
        int v = base + n;
        sH[n][k] = (v < N) ? h1[(size_t)v * 128 + k] : 0.f;
    }
    for (int q = t; q < NPB2 * 32; q += 256) {
        int n = q >> 5, k = q & 31;
        int v = base + n;
        sEA[n][k] = (v < N) ? EA[(size_t)v * 32 + k] : 0.f;
    }
    if (t < NPB2) {
        int v = base + t;
        sCnt[t] = (v < N) ? (float)deg[v] : 0.f;
    }
    __syncthreads();

    float acc[4];
#pragma unroll
    for (int n = 0; n < 4; n++) acc[n] = 0.f;

    for (int k = 0; k < 32; k += 4) {
        float w0 = Wme[(k + 0) * 64 + j];
        float w1 = Wme[(k + 1) * 64 + j];
        float w2 = Wme[(k + 2) * 64 + j];
        float w3 = Wme[(k + 3) * 64 + j];
#pragma unroll
        for (int n = 0; n < 4; n++) {
            float4 f = *(const float4*)&sEA[w * 4 + n][k];
            acc[n] += f.x * w0 + f.y * w1 + f.z * w2 + f.w * w3;
        }
    }
    float bm = bmsg[j];
#pragma unroll
    for (int n = 0; n < 4; n++) {
        int v = base + w * 4 + n;
        float sg = (v < N) ? S2g[(size_t)v * 64 + j] : 0.f;
        float c = sCnt[w * 4 + n];
        sAgg[w * 4 + n][j] = (sg + acc[n] + c * bm) / fmaxf(c, 1.0f);
    }
    __syncthreads();

#pragma unroll
    for (int n = 0; n < 4; n++) acc[n] = 0.f;
    for (int k = 0; k < 128; k += 4) {
        float w0 = Wapp[(k + 0) * 64 + j];
        float w1 = Wapp[(k + 1) * 64 + j];
        float w2 = Wapp[(k + 2) * 64 + j];
        float w3 = Wapp[(k + 3) * 64 + j];
#pragma unroll
        for (int n = 0; n < 4; n++) {
            float4 f = *(const float4*)&sH[w * 4 + n][k];
            acc[n] += f.x * w0 + f.y * w1 + f.z * w2 + f.w * w3;
        }
    }
    for (int k = 0; k < 64; k += 4) {
        float w0 = Wapp[(128 + k + 0) * 64 + j];
        float w1 = Wapp[(128 + k + 1) * 64 + j];
        float w2 = Wapp[(128 + k + 2) * 64 + j];
        float w3 = Wapp[(128 + k + 3) * 64 + j];
#pragma unroll
        for (int n = 0; n < 4; n++) {
            float4 f = *(const float4*)&sAgg[w * 4 + n][k];
            acc[n] += f.x * w0 + f.y * w1 + f.z * w2 + f.w * w3;
        }
    }
    float ba = bapp[j];
#pragma unroll
    for (int n = 0; n < 4; n++) {
        int v = base + w * 4 + n;
        if (v < N) out[(size_t)v * 64 + j] = fmaxf(acc[n] + ba, 0.f);
    }
}

// ---------------------------------------------------------------------------
extern "C" void kernel_launch(void* const* d_in, const int* in_sizes, int n_in,
                              void* d_out, int out_size, void* d_ws, size_t ws_size,
                              hipStream_t stream) {
    const float* x      = (const float*)d_in[0];
    const int*   ei     = (const int*)d_in[1];
    const float* ea     = (const float*)d_in[2];
    const float* Wmsg1  = (const float*)d_in[3];
    const float* bmsg1  = (const float*)d_in[4];
    const float* Wapp1  = (const float*)d_in[5];
    const float* bapp1  = (const float*)d_in[6];
    const float* Wmsg2  = (const float*)d_in[7];
    const float* bmsg2  = (const float*)d_in[8];
    const float* Wapp2  = (const float*)d_in[9];
    const float* bapp2  = (const float*)d_in[10];

    const int N = in_sizes[0] / 64;      // 50000
    const int E = in_sizes[1] / 2;       // 800000
    const int NCH = (N + SCAN_CHUNK - 1) / SCAN_CHUNK;
    const int* src = ei;
    const int* dst = ei + E;

    uint8_t* p = (uint8_t*)d_ws;
    auto alloc = [&](size_t bytes) -> void* {
        void* r = (void*)p;
        p += (bytes + 255) & ~(size_t)255;
        return r;
    };
    int*   deg    = (int*)alloc((size_t)N * 4);
    int*   off    = (int*)alloc((size_t)(N + 1) * 4);
    int*   cursor = (int*)alloc((size_t)N * 4);
    int*   part   = (int*)alloc((size_t)NCH * 4);
    int2*  elist  = (int2*)alloc((size_t)E * 8);
    float* S1     = (float*)alloc((size_t)N * 64 * 4);  // reused as S2g
    float* EA     = (float*)alloc((size_t)N * 32 * 4);
    float* h1     = (float*)alloc((size_t)N * 128 * 4);
    float* g2     = (float*)alloc((size_t)N * 64 * 4);
    float* S2g    = S1;   // safe: S1 consumed by node1 before agg2 writes S2g

    hipMemsetAsync(deg, 0, (size_t)N * 4, stream);

    // CSR build
    hist_kernel<<<(E + 255) / 256, 256, 0, stream>>>(dst, deg, E);
    scanA_kernel<<<NCH, 256, 0, stream>>>(deg, part, N);
    scanB_kernel<<<1, 64, 0, stream>>>(part, off + N, NCH);
    scanC_kernel<<<NCH, SCAN_CHUNK, 0, stream>>>(deg, part, off, cursor, N);
    fill_kernel<<<(E + 255) / 256, 256, 0, stream>>>(src, dst, cursor, elist, E);

    // Layer 1
    agg1_kernel<<<(N + 3) / 4, 256, 0, stream>>>(
        (const float4*)x, (const float4*)ea, elist, off,
        (float4*)S1, (float4*)EA, N);
    node1_kernel<<<(N + NPB1 - 1) / NPB1, 512, 0, stream>>>(
        x, S1, EA, deg, Wmsg1, bmsg1, Wapp1, bapp1, Wmsg2,
        h1, g2, N);

    // Layer 2
    agg2_kernel<<<(N + 3) / 4, 256, 0, stream>>>(
        (const float4*)g2, elist, off, (float4*)S2g, N);
    node2_kernel<<<(N + NPB2 - 1) / NPB2, 256, 0, stream>>>(
        h1, S2g, EA, deg, Wmsg2 + 128 * 64, bmsg2, Wapp2, bapp2,
        (float*)d_out, N);
}

// Round 5
// 347.843 us; speedup vs baseline: 7.0538x; 7.0538x over previous
//
#include <hip/hip_runtime.h>

#define SCAN_CHUNK 1024

__device__ inline float4 f4_xor_add(float4 v, int mask) {
    v.x += __shfl_xor(v.x, mask);
    v.y += __shfl_xor(v.y, mask);
    v.z += __shfl_xor(v.z, mask);
    v.w += __shfl_xor(v.w, mask);
    return v;
}

// ---------------------------------------------------------------------------
// CSR build
// ---------------------------------------------------------------------------
__global__ void hist_kernel(const int* __restrict__ dst, int* __restrict__ deg, int E)
{
    int e = blockIdx.x * blockDim.x + threadIdx.x;
    if (e < E) atomicAdd(&deg[dst[e]], 1);
}

__global__ __launch_bounds__(256) void scanA_kernel(const int* __restrict__ deg,
                                                    int* __restrict__ part, int N)
{
    __shared__ int red[256];
    int b = blockIdx.x, t = threadIdx.x;
    int base = b * SCAN_CHUNK;
    int s = 0;
    for (int i = t; i < SCAN_CHUNK; i += 256) {
        int idx = base + i;
        s += (idx < N) ? deg[idx] : 0;
    }
    red[t] = s;
    __syncthreads();
    for (int o = 128; o > 0; o >>= 1) {
        if (t < o) red[t] += red[t + o];
        __syncthreads();
    }
    if (t == 0) part[b] = red[0];
}

__global__ void scanB_kernel(int* __restrict__ part, int* __restrict__ offN, int NCH)
{
    int lane = threadIdx.x;
    int orig = (lane < NCH) ? part[lane] : 0;
    int v = orig;
    for (int s = 1; s < 64; s <<= 1) {
        int t = __shfl_up(v, s);
        if (lane >= s) v += t;
    }
    if (lane < NCH) part[lane] = v - orig;
    if (lane == NCH - 1) *offN = v;
}

__global__ __launch_bounds__(SCAN_CHUNK) void scanC_kernel(const int* __restrict__ deg,
                                                           const int* __restrict__ part,
                                                           int* __restrict__ off,
                                                           int* __restrict__ cursor, int N)
{
    __shared__ int buf[SCAN_CHUNK];
    int b = blockIdx.x, t = threadIdx.x;
    int idx = b * SCAN_CHUNK + t;
    int v = (idx < N) ? deg[idx] : 0;
    buf[t] = v;
    __syncthreads();
    for (int s = 1; s < SCAN_CHUNK; s <<= 1) {
        int tmp = (t >= s) ? buf[t - s] : 0;
        __syncthreads();
        buf[t] += tmp;
        __syncthreads();
    }
    int excl = buf[t] - v + part[b];
    if (idx < N) { off[idx] = excl; cursor[idx] = excl; }
}

__global__ void fill_kernel(const int* __restrict__ src, const int* __restrict__ dst,
                            int* __restrict__ cursor, int2* __restrict__ elist, int E)
{
    int e = blockIdx.x * blockDim.x + threadIdx.x;
    if (e >= E) return;
    int d = dst[e];
    int p = atomicAdd(&cursor[d], 1);
    elist[p] = make_int2(src[e], e);
}

// ---------------------------------------------------------------------------
// Layer-1 aggregate: one wave per node; float4 row gathers.
// ---------------------------------------------------------------------------
__global__ __launch_bounds__(256) void agg1_kernel(const float4* __restrict__ x4,
                                                   const float4* __restrict__ ea4,
                                                   const int2* __restrict__ elist,
                                                   const int* __restrict__ off,
                                                   float4* __restrict__ S1v,
                                                   float4* __restrict__ EAv, int N)
{
    int wv = (blockIdx.x * blockDim.x + threadIdx.x) >> 6;
    int lane = threadIdx.x & 63;
    if (wv >= N) return;
    int beg = off[wv], end = off[wv + 1];

    // x part: 64 feats = 16 float4; 4 rows in flight
    int g4 = lane >> 4, s4 = lane & 15;
    float4 ax = make_float4(0.f, 0.f, 0.f, 0.f);
    for (int i = beg + g4; i < end; i += 4) {
        int row = elist[i].x;
        float4 v = x4[(size_t)row * 16 + s4];
        ax.x += v.x; ax.y += v.y; ax.z += v.z; ax.w += v.w;
    }
    ax = f4_xor_add(ax, 16);
    ax = f4_xor_add(ax, 32);
    if (lane < 16) S1v[(size_t)wv * 16 + s4] = ax;

    // ea part: 32 feats = 8 float4; 8 rows in flight
    int g8 = lane >> 3, s8 = lane & 7;
    float4 ae = make_float4(0.f, 0.f, 0.f, 0.f);
    for (int i = beg + g8; i < end; i += 8) {
        int eid = elist[i].y;
        float4 v = ea4[(size_t)eid * 8 + s8];
        ae.x += v.x; ae.y += v.y; ae.z += v.z; ae.w += v.w;
    }
    ae = f4_xor_add(ae, 8);
    ae = f4_xor_add(ae, 16);
    ae = f4_xor_add(ae, 32);
    if (lane < 8) EAv[(size_t)wv * 8 + s8] = ae;
}

// ---------------------------------------------------------------------------
// Layer-2 aggregate: one wave per node; g2 rows (64f) via 16-lane float4 groups.
// ---------------------------------------------------------------------------
__global__ __launch_bounds__(256) void agg2_kernel(const float4* __restrict__ g24,
                                                   const int2* __restrict__ elist,
                                                   const int* __restrict__ off,
                                                   float4* __restrict__ S2gv, int N)
{
    int wv = (blockIdx.x * blockDim.x + threadIdx.x) >> 6;
    int lane = threadIdx.x & 63;
    if (wv >= N) return;
    int beg = off[wv], end = off[wv + 1];

    int g4 = lane >> 4, s4 = lane & 15;
    float4 ag = make_float4(0.f, 0.f, 0.f, 0.f);
    for (int i = beg + g4; i < end; i += 4) {
        int row = elist[i].x;
        float4 v = g24[(size_t)row * 16 + s4];
        ag.x += v.x; ag.y += v.y; ag.z += v.z; ag.w += v.w;
    }
    ag = f4_xor_add(ag, 16);
    ag = f4_xor_add(ag, 32);
    if (lane < 16) S2gv[(size_t)wv * 16 + s4] = ag;
}

// ---------------------------------------------------------------------------
// Layer-1 node kernel + fused g2 = h1 @ Wmsg2[0:128].
// 256 threads: j = t&127, g = t>>7 (0..1) -> nodes g*8..g*8+7, acc[8].
// #pragma unroll 2 on k-loops prevents full-unroll VGPR blowup (R4 lesson).
// ---------------------------------------------------------------------------
#define NPB1 16
__global__ __launch_bounds__(256) void node1_kernel(
    const float* __restrict__ x,
    const float* __restrict__ S1,
    const float* __restrict__ EA,
    const int*   __restrict__ deg,
    const float* __restrict__ Wmsg,   // [96][128]
    const float* __restrict__ bmsg,   // [128]
    const float* __restrict__ Wapp,   // [192][128]
    const float* __restrict__ bapp,   // [128]
    const float* __restrict__ Wm2h,   // Wmsg2 rows 0..127 -> [128][64]
    float* __restrict__ h1,
    float* __restrict__ g2,
    int N)
{
    __shared__ __align__(16) float sF[NPB1][96];    // [S1 | EA]
    __shared__ __align__(16) float sX[NPB1][64];
    __shared__ __align__(16) float sAgg[NPB1][128];
    __shared__ __align__(16) float sH[NPB1][128];
    __shared__ float sCnt[NPB1];

    int t = threadIdx.x;              // 0..255
    int j = t & 127;                  // output column
    int g = t >> 7;                   // node group 0..1
    int base = blockIdx.x * NPB1;

    for (int q = t; q < NPB1 * 64; q += 256) {
        int n = q >> 6, k = q & 63;
        int v = base + n;
        sF[n][k] = (v < N) ? S1[(size_t)v * 64 + k] : 0.f;
        sX[n][k] = (v < N) ? x[(size_t)v * 64 + k] : 0.f;
    }
    for (int q = t; q < NPB1 * 32; q += 256) {
        int n = q >> 5, k = q & 31;
        int v = base + n;
        sF[n][64 + k] = (v < N) ? EA[(size_t)v * 32 + k] : 0.f;
    }
    if (t < NPB1) {
        int v = base + t;
        sCnt[t] = (v < N) ? (float)deg[v] : 0.f;
    }
    __syncthreads();

    float acc[8];
#pragma unroll
    for (int n = 0; n < 8; n++) acc[n] = 0.f;

#pragma unroll 2
    for (int k = 0; k < 96; k += 4) {
        float w0 = Wmsg[(k + 0) * 128 + j];
        float w1 = Wmsg[(k + 1) * 128 + j];
        float w2 = Wmsg[(k + 2) * 128 + j];
        float w3 = Wmsg[(k + 3) * 128 + j];
#pragma unroll
        for (int n = 0; n < 8; n++) {
            float4 f = *(const float4*)&sF[g * 8 + n][k];
            acc[n] += f.x * w0 + f.y * w1 + f.z * w2 + f.w * w3;
        }
    }
    float bm = bmsg[j];
#pragma unroll
    for (int n = 0; n < 8; n++) {
        float c = sCnt[g * 8 + n];
        sAgg[g * 8 + n][j] = (acc[n] + c * bm) / fmaxf(c, 1.0f);
    }
    __syncthreads();

#pragma unroll
    for (int n = 0; n < 8; n++) acc[n] = 0.f;
#pragma unroll 2
    for (int k = 0; k < 64; k += 4) {
        float w0 = Wapp[(k + 0) * 128 + j];
        float w1 = Wapp[(k + 1) * 128 + j];
        float w2 = Wapp[(k + 2) * 128 + j];
        float w3 = Wapp[(k + 3) * 128 + j];
#pragma unroll
        for (int n = 0; n < 8; n++) {
            float4 f = *(const float4*)&sX[g * 8 + n][k];
            acc[n] += f.x * w0 + f.y * w1 + f.z * w2 + f.w * w3;
        }
    }
#pragma unroll 2
    for (int k = 0; k < 128; k += 4) {
        float w0 = Wapp[(64 + k + 0) * 128 + j];
        float w1 = Wapp[(64 + k + 1) * 128 + j];
        float w2 = Wapp[(64 + k + 2) * 128 + j];
        float w3 = Wapp[(64 + k + 3) * 128 + j];
#pragma unroll
        for (int n = 0; n < 8; n++) {
            float4 f = *(const float4*)&sAgg[g * 8 + n][k];
            acc[n] += f.x * w0 + f.y * w1 + f.z * w2 + f.w * w3;
        }
    }
    float ba = bapp[j];
#pragma unroll
    for (int n = 0; n < 8; n++) {
        int v = base + g * 8 + n;
        float hv = fmaxf(acc[n] + ba, 0.f);
        sH[g * 8 + n][j] = hv;
        if (v < N) h1[(size_t)v * 128 + j] = hv;
    }
    __syncthreads();

    // g2 = sH @ Wm2h (128 -> 64): col = t&63, q = t>>6 (0..3) -> 4 nodes each
    int col = t & 63;
    int qg = t >> 6;
    float ga[4];
#pragma unroll
    for (int n = 0; n < 4; n++) ga[n] = 0.f;
#pragma unroll 2
    for (int k = 0; k < 128; k += 4) {
        float w0 = Wm2h[(k + 0) * 64 + col];
        float w1 = Wm2h[(k + 1) * 64 + col];
        float w2 = Wm2h[(k + 2) * 64 + col];
        float w3 = Wm2h[(k + 3) * 64 + col];
#pragma unroll
        for (int n = 0; n < 4; n++) {
            float4 f = *(const float4*)&sH[qg * 4 + n][k];
            ga[n] += f.x * w0 + f.y * w1 + f.z * w2 + f.w * w3;
        }
    }
#pragma unroll
    for (int n = 0; n < 4; n++) {
        int v = base + qg * 4 + n;
        if (v < N) g2[(size_t)v * 64 + col] = ga[n];
    }
}

// ---------------------------------------------------------------------------
// Layer-2 node kernel. 256 threads: j = t&63, w = t>>6 -> nodes w*4..w*4+3.
// ---------------------------------------------------------------------------
#define NPB2 16
__global__ __launch_bounds__(256) void node2_kernel(
    const float* __restrict__ h1,
    const float* __restrict__ S2g,
    const float* __restrict__ EA,
    const int*   __restrict__ deg,
    const float* __restrict__ Wme,    // Wmsg2 rows 128..159 -> [32][64]
    const float* __restrict__ bmsg,   // [64]
    const float* __restrict__ Wapp,   // [192][64]
    const float* __restrict__ bapp,   // [64]
    float* __restrict__ out,
    int N)
{
    __shared__ __align__(16) float sEA[NPB2][32];
    __shared__ __align__(16) float sH[NPB2][128];
    __shared__ __align__(16) float sAgg[NPB2][64];
    __shared__ float sCnt[NPB2];

    int t = threadIdx.x;              // 0..255
    int j = t & 63;                   // output column
    int w = t >> 6;                   // node group 0..3
    int base = blockIdx.x * NPB2;

    for (int q = t; q < NPB2 * 128; q += 256) {
        int n = q >> 7, k = q & 127;
        int v = base + n;
        sH[n][k] = (v < N) ? h1[(size_t)v * 128 + k] : 0.f;
    }
    for (int q = t; q < NPB2 * 32; q += 256) {
        int n = q >> 5, k = q & 31;
        int v = base + n;
        sEA[n][k] = (v < N) ? EA[(size_t)v * 32 + k] : 0.f;
    }
    if (t < NPB2) {
        int v = base + t;
        sCnt[t] = (v < N) ? (float)deg[v] : 0.f;
    }
    __syncthreads();

    float acc[4];
#pragma unroll
    for (int n = 0; n < 4; n++) acc[n] = 0.f;

#pragma unroll 2
    for (int k = 0; k < 32; k += 4) {
        float w0 = Wme[(k + 0) * 64 + j];
        float w1 = Wme[(k + 1) * 64 + j];
        float w2 = Wme[(k + 2) * 64 + j];
        float w3 = Wme[(k + 3) * 64 + j];
#pragma unroll
        for (int n = 0; n < 4; n++) {
            float4 f = *(const float4*)&sEA[w * 4 + n][k];
            acc[n] += f.x * w0 + f.y * w1 + f.z * w2 + f.w * w3;
        }
    }
    float bm = bmsg[j];
#pragma unroll
    for (int n = 0; n < 4; n++) {
        int v = base + w * 4 + n;
        float sg = (v < N) ? S2g[(size_t)v * 64 + j] : 0.f;
        float c = sCnt[w * 4 + n];
        sAgg[w * 4 + n][j] = (sg + acc[n] + c * bm) / fmaxf(c, 1.0f);
    }
    __syncthreads();

#pragma unroll
    for (int n = 0; n < 4; n++) acc[n] = 0.f;
#pragma unroll 2
    for (int k = 0; k < 128; k += 4) {
        float w0 = Wapp[(k + 0) * 64 + j];
        float w1 = Wapp[(k + 1) * 64 + j];
        float w2 = Wapp[(k + 2) * 64 + j];
        float w3 = Wapp[(k + 3) * 64 + j];
#pragma unroll
        for (int n = 0; n < 4; n++) {
            float4 f = *(const float4*)&sH[w * 4 + n][k];
            acc[n] += f.x * w0 + f.y * w1 + f.z * w2 + f.w * w3;
        }
    }
#pragma unroll 2
    for (int k = 0; k < 64; k += 4) {
        float w0 = Wapp[(128 + k + 0) * 64 + j];
        float w1 = Wapp[(128 + k + 1) * 64 + j];
        float w2 = Wapp[(128 + k + 2) * 64 + j];
        float w3 = Wapp[(128 + k + 3) * 64 + j];
#pragma unroll
        for (int n = 0; n < 4; n++) {
            float4 f = *(const float4*)&sAgg[w * 4 + n][k];
            acc[n] += f.x * w0 + f.y * w1 + f.z * w2 + f.w * w3;
        }
    }
    float ba = bapp[j];
#pragma unroll
    for (int n = 0; n < 4; n++) {
        int v = base + w * 4 + n;
        if (v < N) out[(size_t)v * 64 + j] = fmaxf(acc[n] + ba, 0.f);
    }
}

// ---------------------------------------------------------------------------
extern "C" void kernel_launch(void* const* d_in, const int* in_sizes, int n_in,
                              void* d_out, int out_size, void* d_ws, size_t ws_size,
                              hipStream_t stream) {
    const float* x      = (const float*)d_in[0];
    const int*   ei     = (const int*)d_in[1];
    const float* ea     = (const float*)d_in[2];
    const float* Wmsg1  = (const float*)d_in[3];
    const float* bmsg1  = (const float*)d_in[4];
    const float* Wapp1  = (const float*)d_in[5];
    const float* bapp1  = (const float*)d_in[6];
    const float* Wmsg2  = (const float*)d_in[7];
    const float* bmsg2  = (const float*)d_in[8];
    const float* Wapp2  = (const float*)d_in[9];
    const float* bapp2  = (const float*)d_in[10];

    const int N = in_sizes[0] / 64;      // 50000
    const int E = in_sizes[1] / 2;       // 800000
    const int NCH = (N + SCAN_CHUNK - 1) / SCAN_CHUNK;
    const int* src = ei;
    const int* dst = ei + E;

    uint8_t* p = (uint8_t*)d_ws;
    auto alloc = [&](size_t bytes) -> void* {
        void* r = (void*)p;
        p += (bytes + 255) & ~(size_t)255;
        return r;
    };
    int*   deg    = (int*)alloc((size_t)N * 4);
    int*   off    = (int*)alloc((size_t)(N + 1) * 4);
    int*   cursor = (int*)alloc((size_t)N * 4);
    int*   part   = (int*)alloc((size_t)NCH * 4);
    int2*  elist  = (int2*)alloc((size_t)E * 8);
    float* S1     = (float*)alloc((size_t)N * 64 * 4);  // reused as S2g
    float* EA     = (float*)alloc((size_t)N * 32 * 4);
    float* h1     = (float*)alloc((size_t)N * 128 * 4);
    float* g2     = (float*)alloc((size_t)N * 64 * 4);
    float* S2g    = S1;   // safe: S1 consumed by node1 before agg2 writes S2g

    hipMemsetAsync(deg, 0, (size_t)N * 4, stream);

    // CSR build
    hist_kernel<<<(E + 255) / 256, 256, 0, stream>>>(dst, deg, E);
    scanA_kernel<<<NCH, 256, 0, stream>>>(deg, part, N);
    scanB_kernel<<<1, 64, 0, stream>>>(part, off + N, NCH);
    scanC_kernel<<<NCH, SCAN_CHUNK, 0, stream>>>(deg, part, off, cursor, N);
    fill_kernel<<<(E + 255) / 256, 256, 0, stream>>>(src, dst, cursor, elist, E);

    // Layer 1
    agg1_kernel<<<(N + 3) / 4, 256, 0, stream>>>(
        (const float4*)x, (const float4*)ea, elist, off,
        (float4*)S1, (float4*)EA, N);
    node1_kernel<<<(N + NPB1 - 1) / NPB1, 256, 0, stream>>>(
        x, S1, EA, deg, Wmsg1, bmsg1, Wapp1, bapp1, Wmsg2,
        h1, g2, N);

    // Layer 2
    agg2_kernel<<<(N + 3) / 4, 256, 0, stream>>>(
        (const float4*)g2, elist, off, (float4*)S2g, N);
    node2_kernel<<<(N + NPB2 - 1) / NPB2, 256, 0, stream>>>(
        h1, S2g, EA, deg, Wmsg2 + 128 * 64, bmsg2, Wapp2, bapp2,
        (float*)d_out, N);
}

// Round 6
// 301.109 us; speedup vs baseline: 8.1486x; 1.1552x over previous
//
#include <hip/hip_runtime.h>

#define SCAN_CHUNK 1024

__device__ inline float4 f4_xor_add(float4 v, int mask) {
    v.x += __shfl_xor(v.x, mask);
    v.y += __shfl_xor(v.y, mask);
    v.z += __shfl_xor(v.z, mask);
    v.w += __shfl_xor(v.w, mask);
    return v;
}

// ---------------------------------------------------------------------------
// CSR build
// ---------------------------------------------------------------------------
__global__ void hist_kernel(const int* __restrict__ dst, int* __restrict__ deg, int E)
{
    int e = blockIdx.x * blockDim.x + threadIdx.x;
    if (e < E) atomicAdd(&deg[dst[e]], 1);
}

__global__ __launch_bounds__(256) void scanA_kernel(const int* __restrict__ deg,
                                                    int* __restrict__ part, int N)
{
    __shared__ int red[256];
    int b = blockIdx.x, t = threadIdx.x;
    int base = b * SCAN_CHUNK;
    int s = 0;
    for (int i = t; i < SCAN_CHUNK; i += 256) {
        int idx = base + i;
        s += (idx < N) ? deg[idx] : 0;
    }
    red[t] = s;
    __syncthreads();
    for (int o = 128; o > 0; o >>= 1) {
        if (t < o) red[t] += red[t + o];
        __syncthreads();
    }
    if (t == 0) part[b] = red[0];
}

__global__ void scanB_kernel(int* __restrict__ part, int* __restrict__ offN, int NCH)
{
    int lane = threadIdx.x;
    int orig = (lane < NCH) ? part[lane] : 0;
    int v = orig;
    for (int s = 1; s < 64; s <<= 1) {
        int t = __shfl_up(v, s);
        if (lane >= s) v += t;
    }
    if (lane < NCH) part[lane] = v - orig;
    if (lane == NCH - 1) *offN = v;
}

__global__ __launch_bounds__(SCAN_CHUNK) void scanC_kernel(const int* __restrict__ deg,
                                                           const int* __restrict__ part,
                                                           int* __restrict__ off,
                                                           int* __restrict__ cursor, int N)
{
    __shared__ int buf[SCAN_CHUNK];
    int b = blockIdx.x, t = threadIdx.x;
    int idx = b * SCAN_CHUNK + t;
    int v = (idx < N) ? deg[idx] : 0;
    buf[t] = v;
    __syncthreads();
    for (int s = 1; s < SCAN_CHUNK; s <<= 1) {
        int tmp = (t >= s) ? buf[t - s] : 0;
        __syncthreads();
        buf[t] += tmp;
        __syncthreads();
    }
    int excl = buf[t] - v + part[b];
    if (idx < N) { off[idx] = excl; cursor[idx] = excl; }
}

__global__ void fill_kernel(const int* __restrict__ src, const int* __restrict__ dst,
                            int* __restrict__ cursor, int2* __restrict__ elist, int E)
{
    int e = blockIdx.x * blockDim.x + threadIdx.x;
    if (e >= E) return;
    int d = dst[e];
    int p = atomicAdd(&cursor[d], 1);
    elist[p] = make_int2(src[e], e);
}

// ---------------------------------------------------------------------------
// Weight composition (layer 1):
// Wc1[160][128]: rows 0-63  = Wapp1[0:64]           (x part)
//                rows 64-159= Wmsg1 @ Wapp1[64:192] (aggr part, incl. ea rows)
// bmW1 = bmsg1 @ Wapp1[64:192]; b1eff = bapp1 + bmW1
// ---------------------------------------------------------------------------
__global__ __launch_bounds__(128) void compose1_kernel(
    const float* __restrict__ Wmsg1, const float* __restrict__ bmsg1,
    const float* __restrict__ Wapp1, const float* __restrict__ bapp1,
    float* __restrict__ Wc1, float* __restrict__ b1eff, float* __restrict__ bmW1)
{
    int b = blockIdx.x;   // 0..160
    int j = threadIdx.x;  // 0..127
    if (b < 64) {
        Wc1[b * 128 + j] = Wapp1[b * 128 + j];
    } else if (b < 160) {
        int ar = b - 64;  // Wmsg1 row (0..95)
        float s = 0.f;
        for (int k = 0; k < 128; k++)
            s = fmaf(Wmsg1[ar * 128 + k], Wapp1[(64 + k) * 128 + j], s);
        Wc1[b * 128 + j] = s;
    } else {
        float s = 0.f;
        for (int k = 0; k < 128; k++)
            s = fmaf(bmsg1[k], Wapp1[(64 + k) * 128 + j], s);
        bmW1[j] = s;
        b1eff[j] = bapp1[j] + s;
    }
}

// ---------------------------------------------------------------------------
// Weight composition (layer 2):
// Wc2[224][64]: rows 0-191  = Wapp2 (h part + A2g identity-composed part)
//               rows 192-223= Wmsg2[128:160] @ Wapp2[128:192] (ea part)
// bmW2 = bmsg2 @ Wapp2[128:192]; b2eff = bapp2 + bmW2
// ---------------------------------------------------------------------------
__global__ __launch_bounds__(64) void compose2_kernel(
    const float* __restrict__ Wmsg2, const float* __restrict__ bmsg2,
    const float* __restrict__ Wapp2, const float* __restrict__ bapp2,
    float* __restrict__ Wc2, float* __restrict__ b2eff, float* __restrict__ bmW2)
{
    int b = blockIdx.x;  // 0..224
    int j = threadIdx.x; // 0..63
    if (b < 192) {
        Wc2[b * 64 + j] = Wapp2[b * 64 + j];
    } else if (b < 224) {
        int ar = 128 + (b - 192);  // Wmsg2 row (ea part)
        float s = 0.f;
        for (int k = 0; k < 64; k++)
            s = fmaf(Wmsg2[ar * 64 + k], Wapp2[(128 + k) * 64 + j], s);
        Wc2[b * 64 + j] = s;
    } else {
        float s = 0.f;
        for (int k = 0; k < 64; k++)
            s = fmaf(bmsg2[k], Wapp2[(128 + k) * 64 + j], s);
        bmW2[j] = s;
        b2eff[j] = bapp2[j] + s;
    }
}

// ---------------------------------------------------------------------------
// Layer-1 aggregate: one wave per node; float4 row gathers; normalized output.
// ---------------------------------------------------------------------------
__global__ __launch_bounds__(256) void agg1_kernel(const float4* __restrict__ x4,
                                                   const float4* __restrict__ ea4,
                                                   const int2* __restrict__ elist,
                                                   const int* __restrict__ off,
                                                   float4* __restrict__ A1x,
                                                   float4* __restrict__ A1e, int N)
{
    int wv = (blockIdx.x * blockDim.x + threadIdx.x) >> 6;
    int lane = threadIdx.x & 63;
    if (wv >= N) return;
    int beg = off[wv], end = off[wv + 1];
    float c = fmaxf((float)(end - beg), 1.0f);

    // x part: 64 feats = 16 float4; 4 rows in flight
    int g4 = lane >> 4, s4 = lane & 15;
    float4 ax = make_float4(0.f, 0.f, 0.f, 0.f);
    for (int i = beg + g4; i < end; i += 4) {
        int row = elist[i].x;
        float4 v = x4[(size_t)row * 16 + s4];
        ax.x += v.x; ax.y += v.y; ax.z += v.z; ax.w += v.w;
    }
    ax = f4_xor_add(ax, 16);
    ax = f4_xor_add(ax, 32);
    if (lane < 16) {
        ax.x /= c; ax.y /= c; ax.z /= c; ax.w /= c;
        A1x[(size_t)wv * 16 + s4] = ax;
    }

    // ea part: 32 feats = 8 float4; 8 rows in flight
    int g8 = lane >> 3, s8 = lane & 7;
    float4 ae = make_float4(0.f, 0.f, 0.f, 0.f);
    for (int i = beg + g8; i < end; i += 8) {
        int eid = elist[i].y;
        float4 v = ea4[(size_t)eid * 8 + s8];
        ae.x += v.x; ae.y += v.y; ae.z += v.z; ae.w += v.w;
    }
    ae = f4_xor_add(ae, 8);
    ae = f4_xor_add(ae, 16);
    ae = f4_xor_add(ae, 32);
    if (lane < 8) {
        ae.x /= c; ae.y /= c; ae.z /= c; ae.w /= c;
        A1e[(size_t)wv * 8 + s8] = ae;
    }
}

// ---------------------------------------------------------------------------
// Layer-2 aggregate: one wave per node; normalized.
// ---------------------------------------------------------------------------
__global__ __launch_bounds__(256) void agg2_kernel(const float4* __restrict__ g24,
                                                   const int2* __restrict__ elist,
                                                   const int* __restrict__ off,
                                                   float4* __restrict__ A2g, int N)
{
    int wv = (blockIdx.x * blockDim.x + threadIdx.x) >> 6;
    int lane = threadIdx.x & 63;
    if (wv >= N) return;
    int beg = off[wv], end = off[wv + 1];
    float c = fmaxf((float)(end - beg), 1.0f);

    int g4 = lane >> 4, s4 = lane & 15;
    float4 ag = make_float4(0.f, 0.f, 0.f, 0.f);
    for (int i = beg + g4; i < end; i += 4) {
        int row = elist[i].x;
        float4 v = g24[(size_t)row * 16 + s4];
        ag.x += v.x; ag.y += v.y; ag.z += v.z; ag.w += v.w;
    }
    ag = f4_xor_add(ag, 16);
    ag = f4_xor_add(ag, 32);
    if (lane < 16) {
        ag.x /= c; ag.y /= c; ag.z /= c; ag.w /= c;
        A2g[(size_t)wv * 16 + s4] = ag;
    }
}

// ---------------------------------------------------------------------------
// Layer-1 node kernel: h1 = relu([x|A1x|A1e] @ Wc1 + b1eff) ; g2 = h1 @ Wm2h
// 256 threads: j=t&127, g=t>>7 -> nodes g*8..g*8+7, acc[8].
// ---------------------------------------------------------------------------
#define NPB1 16
__global__ __launch_bounds__(256) void node1_kernel(
    const float* __restrict__ x,
    const float* __restrict__ A1x,
    const float* __restrict__ A1e,
    const int*   __restrict__ deg,
    const float* __restrict__ Wc1,    // [160][128]
    const float* __restrict__ b1eff,  // [128]
    const float* __restrict__ bmW1,   // [128]
    const float* __restrict__ Wm2h,   // Wmsg2 rows 0..127 -> [128][64]
    float* __restrict__ h1,
    float* __restrict__ g2,
    int N)
{
    __shared__ __align__(16) float sF[NPB1][160];   // [x | A1x | A1e]
    __shared__ __align__(16) float sH[NPB1][128];
    __shared__ float sCnt[NPB1];

    int t = threadIdx.x;              // 0..255
    int j = t & 127;                  // output column
    int g = t >> 7;                   // node group 0..1
    int base = blockIdx.x * NPB1;

    for (int q = t; q < NPB1 * 64; q += 256) {
        int n = q >> 6, k = q & 63;
        int v = base + n;
        sF[n][k]      = (v < N) ? x[(size_t)v * 64 + k]   : 0.f;
        sF[n][64 + k] = (v < N) ? A1x[(size_t)v * 64 + k] : 0.f;
    }
    for (int q = t; q < NPB1 * 32; q += 256) {
        int n = q >> 5, k = q & 31;
        int v = base + n;
        sF[n][128 + k] = (v < N) ? A1e[(size_t)v * 32 + k] : 0.f;
    }
    if (t < NPB1) {
        int v = base + t;
        sCnt[t] = (v < N) ? (float)deg[v] : 1.f;
    }
    __syncthreads();

    float acc[8];
#pragma unroll
    for (int n = 0; n < 8; n++) acc[n] = 0.f;

#pragma unroll 2
    for (int k = 0; k < 160; k += 4) {
        float w0 = Wc1[(k + 0) * 128 + j];
        float w1 = Wc1[(k + 1) * 128 + j];
        float w2 = Wc1[(k + 2) * 128 + j];
        float w3 = Wc1[(k + 3) * 128 + j];
#pragma unroll
        for (int n = 0; n < 8; n++) {
            const float4 f = *(const float4*)&sF[g * 8 + n][k];
            acc[n] = fmaf(f.x, w0, acc[n]);
            acc[n] = fmaf(f.y, w1, acc[n]);
            acc[n] = fmaf(f.z, w2, acc[n]);
            acc[n] = fmaf(f.w, w3, acc[n]);
        }
    }
    float b1 = b1eff[j];
    float bw = bmW1[j];
#pragma unroll
    for (int n = 0; n < 8; n++) {
        int v = base + g * 8 + n;
        float bias = (sCnt[g * 8 + n] > 0.f) ? b1 : (b1 - bw);
        float hv = fmaxf(acc[n] + bias, 0.f);
        sH[g * 8 + n][j] = hv;
        if (v < N) h1[(size_t)v * 128 + j] = hv;
    }
    __syncthreads();

    // g2 = sH @ Wm2h (128 -> 64): col=t&63, qg=t>>6 (0..3) -> 4 nodes each
    int col = t & 63;
    int qg = t >> 6;
    float ga[4];
#pragma unroll
    for (int n = 0; n < 4; n++) ga[n] = 0.f;
#pragma unroll 2
    for (int k = 0; k < 128; k += 4) {
        float w0 = Wm2h[(k + 0) * 64 + col];
        float w1 = Wm2h[(k + 1) * 64 + col];
        float w2 = Wm2h[(k + 2) * 64 + col];
        float w3 = Wm2h[(k + 3) * 64 + col];
#pragma unroll
        for (int n = 0; n < 4; n++) {
            const float4 f = *(const float4*)&sH[qg * 4 + n][k];
            ga[n] = fmaf(f.x, w0, ga[n]);
            ga[n] = fmaf(f.y, w1, ga[n]);
            ga[n] = fmaf(f.z, w2, ga[n]);
            ga[n] = fmaf(f.w, w3, ga[n]);
        }
    }
#pragma unroll
    for (int n = 0; n < 4; n++) {
        int v = base + qg * 4 + n;
        if (v < N) g2[(size_t)v * 64 + col] = ga[n];
    }
}

// ---------------------------------------------------------------------------
// Layer-2 node kernel: out = relu([h1|A2g|A1e] @ Wc2 + b2eff)
// 256 threads: j=t&63, w=t>>6 -> nodes w*4..w*4+3, acc[4].
// ---------------------------------------------------------------------------
#define NPB2 16
__global__ __launch_bounds__(256) void node2_kernel(
    const float* __restrict__ h1,
    const float* __restrict__ A2g,
    const float* __restrict__ A1e,
    const int*   __restrict__ deg,
    const float* __restrict__ Wc2,    // [224][64]
    const float* __restrict__ b2eff,  // [64]
    const float* __restrict__ bmW2,   // [64]
    float* __restrict__ out,
    int N)
{
    __shared__ __align__(16) float sF[NPB2][224];   // [h1 | A2g | A1e]
    __shared__ float sCnt[NPB2];

    int t = threadIdx.x;              // 0..255
    int j = t & 63;                   // output column
    int w = t >> 6;                   // node group 0..3
    int base = blockIdx.x * NPB2;

    for (int q = t; q < NPB2 * 128; q += 256) {
        int n = q >> 7, k = q & 127;
        int v = base + n;
        sF[n][k] = (v < N) ? h1[(size_t)v * 128 + k] : 0.f;
    }
    for (int q = t; q < NPB2 * 64; q += 256) {
        int n = q >> 6, k = q & 63;
        int v = base + n;
        sF[n][128 + k] = (v < N) ? A2g[(size_t)v * 64 + k] : 0.f;
    }
    for (int q = t; q < NPB2 * 32; q += 256) {
        int n = q >> 5, k = q & 31;
        int v = base + n;
        sF[n][192 + k] = (v < N) ? A1e[(size_t)v * 32 + k] : 0.f;
    }
    if (t < NPB2) {
        int v = base + t;
        sCnt[t] = (v < N) ? (float)deg[v] : 1.f;
    }
    __syncthreads();

    float acc[4];
#pragma unroll
    for (int n = 0; n < 4; n++) acc[n] = 0.f;

#pragma unroll 2
    for (int k = 0; k < 224; k += 4) {
        float w0 = Wc2[(k + 0) * 64 + j];
        float w1 = Wc2[(k + 1) * 64 + j];
        float w2 = Wc2[(k + 2) * 64 + j];
        float w3 = Wc2[(k + 3) * 64 + j];
#pragma unroll
        for (int n = 0; n < 4; n++) {
            const float4 f = *(const float4*)&sF[w * 4 + n][k];
            acc[n] = fmaf(f.x, w0, acc[n]);
            acc[n] = fmaf(f.y, w1, acc[n]);
            acc[n] = fmaf(f.z, w2, acc[n]);
            acc[n] = fmaf(f.w, w3, acc[n]);
        }
    }
    float b2 = b2eff[j];
    float bw = bmW2[j];
#pragma unroll
    for (int n = 0; n < 4; n++) {
        int v = base + w * 4 + n;
        float bias = (sCnt[w * 4 + n] > 0.f) ? b2 : (b2 - bw);
        if (v < N) out[(size_t)v * 64 + j] = fmaxf(acc[n] + bias, 0.f);
    }
}

// ---------------------------------------------------------------------------
extern "C" void kernel_launch(void* const* d_in, const int* in_sizes, int n_in,
                              void* d_out, int out_size, void* d_ws, size_t ws_size,
                              hipStream_t stream) {
    const float* x      = (const float*)d_in[0];
    const int*   ei     = (const int*)d_in[1];
    const float* ea     = (const float*)d_in[2];
    const float* Wmsg1  = (const float*)d_in[3];
    const float* bmsg1  = (const float*)d_in[4];
    const float* Wapp1  = (const float*)d_in[5];
    const float* bapp1  = (const float*)d_in[6];
    const float* Wmsg2  = (const float*)d_in[7];
    const float* bmsg2  = (const float*)d_in[8];
    const float* Wapp2  = (const float*)d_in[9];
    const float* bapp2  = (const float*)d_in[10];

    const int N = in_sizes[0] / 64;      // 50000
    const int E = in_sizes[1] / 2;       // 800000
    const int NCH = (N + SCAN_CHUNK - 1) / SCAN_CHUNK;
    const int* src = ei;
    const int* dst = ei + E;

    uint8_t* p = (uint8_t*)d_ws;
    auto alloc = [&](size_t bytes) -> void* {
        void* r = (void*)p;
        p += (bytes + 255) & ~(size_t)255;
        return r;
    };
    int*   deg    = (int*)alloc((size_t)N * 4);
    int*   off    = (int*)alloc((size_t)(N + 1) * 4);
    int*   cursor = (int*)alloc((size_t)N * 4);
    int*   part   = (int*)alloc((size_t)NCH * 4);
    int2*  elist  = (int2*)alloc((size_t)E * 8);
    float* A1x    = (float*)alloc((size_t)N * 64 * 4);  // reused as A2g
    float* A1e    = (float*)alloc((size_t)N * 32 * 4);
    float* h1     = (float*)alloc((size_t)N * 128 * 4);
    float* g2     = (float*)alloc((size_t)N * 64 * 4);
    float* Wc1    = (float*)alloc(160 * 128 * 4);
    float* b1eff  = (float*)alloc(128 * 4);
    float* bmW1   = (float*)alloc(128 * 4);
    float* Wc2    = (float*)alloc(224 * 64 * 4);
    float* b2eff  = (float*)alloc(64 * 4);
    float* bmW2   = (float*)alloc(64 * 4);
    float* A2g    = A1x;   // safe: A1x consumed by node1 before agg2 writes A2g

    hipMemsetAsync(deg, 0, (size_t)N * 4, stream);

    // Weight composition (independent of CSR build; tiny)
    compose1_kernel<<<161, 128, 0, stream>>>(Wmsg1, bmsg1, Wapp1, bapp1,
                                             Wc1, b1eff, bmW1);
    compose2_kernel<<<225, 64, 0, stream>>>(Wmsg2, bmsg2, Wapp2, bapp2,
                                            Wc2, b2eff, bmW2);

    // CSR build
    hist_kernel<<<(E + 255) / 256, 256, 0, stream>>>(dst, deg, E);
    scanA_kernel<<<NCH, 256, 0, stream>>>(deg, part, N);
    scanB_kernel<<<1, 64, 0, stream>>>(part, off + N, NCH);
    scanC_kernel<<<NCH, SCAN_CHUNK, 0, stream>>>(deg, part, off, cursor, N);
    fill_kernel<<<(E + 255) / 256, 256, 0, stream>>>(src, dst, cursor, elist, E);

    // Layer 1
    agg1_kernel<<<(N + 3) / 4, 256, 0, stream>>>(
        (const float4*)x, (const float4*)ea, elist, off,
        (float4*)A1x, (float4*)A1e, N);
    node1_kernel<<<(N + NPB1 - 1) / NPB1, 256, 0, stream>>>(
        x, A1x, A1e, deg, Wc1, b1eff, bmW1, Wmsg2 /* rows 0..127 = Wm2h */,
        h1, g2, N);

    // Layer 2
    agg2_kernel<<<(N + 3) / 4, 256, 0, stream>>>(
        (const float4*)g2, elist, off, (float4*)A2g, N);
    node2_kernel<<<(N + NPB2 - 1) / NPB2, 256, 0, stream>>>(
        h1, A2g, A1e, deg, Wc2, b2eff, bmW2,
        (float*)d_out, N);
}

// Round 7
// 283.041 us; speedup vs baseline: 8.6688x; 1.0638x over previous
//
#include <hip/hip_runtime.h>

#define SCAN_CHUNK 1024

__device__ inline float4 f4_xor_add(float4 v, int mask) {
    v.x += __shfl_xor(v.x, mask);
    v.y += __shfl_xor(v.y, mask);
    v.z += __shfl_xor(v.z, mask);
    v.w += __shfl_xor(v.w, mask);
    return v;
}

// bf16 helpers (RNE pack, bit-op unpack)
__device__ inline unsigned int pack_bf16x2(float a, float b) {
    unsigned int ua = __float_as_uint(a);
    unsigned int ub = __float_as_uint(b);
    ua += 0x7FFFu + ((ua >> 16) & 1u);
    ub += 0x7FFFu + ((ub >> 16) & 1u);
    return (ua >> 16) | (ub & 0xFFFF0000u);
}
__device__ inline float bf_lo(unsigned int u) { return __uint_as_float(u << 16); }
__device__ inline float bf_hi(unsigned int u) { return __uint_as_float(u & 0xFFFF0000u); }

// ---------------------------------------------------------------------------
// x fp32 -> bf16 (one float4 -> uint2 per thread)
// ---------------------------------------------------------------------------
__global__ void cvt_x_kernel(const float4* __restrict__ xin,
                             uint2* __restrict__ xb, int n4)
{
    int i = blockIdx.x * blockDim.x + threadIdx.x;
    if (i < n4) {
        float4 v = xin[i];
        uint2 o;
        o.x = pack_bf16x2(v.x, v.y);
        o.y = pack_bf16x2(v.z, v.w);
        xb[i] = o;
    }
}

// ---------------------------------------------------------------------------
// CSR build
// ---------------------------------------------------------------------------
__global__ void hist_kernel(const int* __restrict__ dst, int* __restrict__ deg, int E)
{
    int e = blockIdx.x * blockDim.x + threadIdx.x;
    if (e < E) atomicAdd(&deg[dst[e]], 1);
}

__global__ __launch_bounds__(256) void scanA_kernel(const int* __restrict__ deg,
                                                    int* __restrict__ part, int N)
{
    __shared__ int red[256];
    int b = blockIdx.x, t = threadIdx.x;
    int base = b * SCAN_CHUNK;
    int s = 0;
    for (int i = t; i < SCAN_CHUNK; i += 256) {
        int idx = base + i;
        s += (idx < N) ? deg[idx] : 0;
    }
    red[t] = s;
    __syncthreads();
    for (int o = 128; o > 0; o >>= 1) {
        if (t < o) red[t] += red[t + o];
        __syncthreads();
    }
    if (t == 0) part[b] = red[0];
}

__global__ void scanB_kernel(int* __restrict__ part, int* __restrict__ offN, int NCH)
{
    int lane = threadIdx.x;
    int orig = (lane < NCH) ? part[lane] : 0;
    int v = orig;
    for (int s = 1; s < 64; s <<= 1) {
        int t = __shfl_up(v, s);
        if (lane >= s) v += t;
    }
    if (lane < NCH) part[lane] = v - orig;
    if (lane == NCH - 1) *offN = v;
}

__global__ __launch_bounds__(SCAN_CHUNK) void scanC_kernel(const int* __restrict__ deg,
                                                           const int* __restrict__ part,
                                                           int* __restrict__ off,
                                                           int* __restrict__ cursor, int N)
{
    __shared__ int buf[SCAN_CHUNK];
    int b = blockIdx.x, t = threadIdx.x;
    int idx = b * SCAN_CHUNK + t;
    int v = (idx < N) ? deg[idx] : 0;
    buf[t] = v;
    __syncthreads();
    for (int s = 1; s < SCAN_CHUNK; s <<= 1) {
        int tmp = (t >= s) ? buf[t - s] : 0;
        __syncthreads();
        buf[t] += tmp;
        __syncthreads();
    }
    int excl = buf[t] - v + part[b];
    if (idx < N) { off[idx] = excl; cursor[idx] = excl; }
}

__global__ void fill_kernel(const int* __restrict__ src, const int* __restrict__ dst,
                            int* __restrict__ cursor, int2* __restrict__ elist, int E)
{
    int e = blockIdx.x * blockDim.x + threadIdx.x;
    if (e >= E) return;
    int d = dst[e];
    int p = atomicAdd(&cursor[d], 1);
    elist[p] = make_int2(src[e], e);
}

// ---------------------------------------------------------------------------
// Weight composition (layer 1)
// ---------------------------------------------------------------------------
__global__ __launch_bounds__(128) void compose1_kernel(
    const float* __restrict__ Wmsg1, const float* __restrict__ bmsg1,
    const float* __restrict__ Wapp1, const float* __restrict__ bapp1,
    float* __restrict__ Wc1, float* __restrict__ b1eff, float* __restrict__ bmW1)
{
    int b = blockIdx.x;   // 0..160
    int j = threadIdx.x;  // 0..127
    if (b < 64) {
        Wc1[b * 128 + j] = Wapp1[b * 128 + j];
    } else if (b < 160) {
        int ar = b - 64;
        float s = 0.f;
        for (int k = 0; k < 128; k++)
            s = fmaf(Wmsg1[ar * 128 + k], Wapp1[(64 + k) * 128 + j], s);
        Wc1[b * 128 + j] = s;
    } else {
        float s = 0.f;
        for (int k = 0; k < 128; k++)
            s = fmaf(bmsg1[k], Wapp1[(64 + k) * 128 + j], s);
        bmW1[j] = s;
        b1eff[j] = bapp1[j] + s;
    }
}

// ---------------------------------------------------------------------------
// Weight composition (layer 2)
// ---------------------------------------------------------------------------
__global__ __launch_bounds__(64) void compose2_kernel(
    const float* __restrict__ Wmsg2, const float* __restrict__ bmsg2,
    const float* __restrict__ Wapp2, const float* __restrict__ bapp2,
    float* __restrict__ Wc2, float* __restrict__ b2eff, float* __restrict__ bmW2)
{
    int b = blockIdx.x;  // 0..224
    int j = threadIdx.x; // 0..63
    if (b < 192) {
        Wc2[b * 64 + j] = Wapp2[b * 64 + j];
    } else if (b < 224) {
        int ar = 128 + (b - 192);
        float s = 0.f;
        for (int k = 0; k < 64; k++)
            s = fmaf(Wmsg2[ar * 64 + k], Wapp2[(128 + k) * 64 + j], s);
        Wc2[b * 64 + j] = s;
    } else {
        float s = 0.f;
        for (int k = 0; k < 64; k++)
            s = fmaf(bmsg2[k], Wapp2[(128 + k) * 64 + j], s);
        bmW2[j] = s;
        b2eff[j] = bapp2[j] + s;
    }
}

// ---------------------------------------------------------------------------
// Layer-1 aggregate: one wave per node.
// x (bf16): 8-lane groups x 16B -> 8 rows in flight. ea (fp32): 8-lane groups.
// ---------------------------------------------------------------------------
__global__ __launch_bounds__(256) void agg1_kernel(const uint4* __restrict__ xb,
                                                   const float4* __restrict__ ea4,
                                                   const int2* __restrict__ elist,
                                                   const int* __restrict__ off,
                                                   float4* __restrict__ A1x,
                                                   float4* __restrict__ A1e, int N)
{
    int wv = (blockIdx.x * blockDim.x + threadIdx.x) >> 6;
    int lane = threadIdx.x & 63;
    if (wv >= N) return;
    int beg = off[wv], end = off[wv + 1];
    float inv = 1.0f / fmaxf((float)(end - beg), 1.0f);

    int g8 = lane >> 3, s8 = lane & 7;

    // x part: 64 bf16 per row = 8 x uint4; lane s8 covers feats s8*8 .. s8*8+7
    float ax[8];
#pragma unroll
    for (int q = 0; q < 8; q++) ax[q] = 0.f;
    for (int i = beg + g8; i < end; i += 8) {
        int row = elist[i].x;
        uint4 v = xb[(size_t)row * 8 + s8];
        ax[0] += bf_lo(v.x); ax[1] += bf_hi(v.x);
        ax[2] += bf_lo(v.y); ax[3] += bf_hi(v.y);
        ax[4] += bf_lo(v.z); ax[5] += bf_hi(v.z);
        ax[6] += bf_lo(v.w); ax[7] += bf_hi(v.w);
    }
#pragma unroll
    for (int m = 8; m <= 32; m <<= 1) {
#pragma unroll
        for (int q = 0; q < 8; q++) ax[q] += __shfl_xor(ax[q], m);
    }
    if (lane < 8) {
        float4 o0 = make_float4(ax[0] * inv, ax[1] * inv, ax[2] * inv, ax[3] * inv);
        float4 o1 = make_float4(ax[4] * inv, ax[5] * inv, ax[6] * inv, ax[7] * inv);
        A1x[(size_t)wv * 16 + s8 * 2 + 0] = o0;
        A1x[(size_t)wv * 16 + s8 * 2 + 1] = o1;
    }

    // ea part: 32 f32 per row = 8 x float4; 8 rows in flight
    float4 ae = make_float4(0.f, 0.f, 0.f, 0.f);
    for (int i = beg + g8; i < end; i += 8) {
        int eid = elist[i].y;
        float4 v = ea4[(size_t)eid * 8 + s8];
        ae.x += v.x; ae.y += v.y; ae.z += v.z; ae.w += v.w;
    }
    ae = f4_xor_add(ae, 8);
    ae = f4_xor_add(ae, 16);
    ae = f4_xor_add(ae, 32);
    if (lane < 8) {
        ae.x *= inv; ae.y *= inv; ae.z *= inv; ae.w *= inv;
        A1e[(size_t)wv * 8 + s8] = ae;
    }
}

// ---------------------------------------------------------------------------
// Layer-2 aggregate: one wave per node; g2 (bf16) rows, 8 in flight.
// ---------------------------------------------------------------------------
__global__ __launch_bounds__(256) void agg2_kernel(const uint4* __restrict__ g2b,
                                                   const int2* __restrict__ elist,
                                                   const int* __restrict__ off,
                                                   float4* __restrict__ A2g, int N)
{
    int wv = (blockIdx.x * blockDim.x + threadIdx.x) >> 6;
    int lane = threadIdx.x & 63;
    if (wv >= N) return;
    int beg = off[wv], end = off[wv + 1];
    float inv = 1.0f / fmaxf((float)(end - beg), 1.0f);

    int g8 = lane >> 3, s8 = lane & 7;
    float ag[8];
#pragma unroll
    for (int q = 0; q < 8; q++) ag[q] = 0.f;
    for (int i = beg + g8; i < end; i += 8) {
        int row = elist[i].x;
        uint4 v = g2b[(size_t)row * 8 + s8];
        ag[0] += bf_lo(v.x); ag[1] += bf_hi(v.x);
        ag[2] += bf_lo(v.y); ag[3] += bf_hi(v.y);
        ag[4] += bf_lo(v.z); ag[5] += bf_hi(v.z);
        ag[6] += bf_lo(v.w); ag[7] += bf_hi(v.w);
    }
#pragma unroll
    for (int m = 8; m <= 32; m <<= 1) {
#pragma unroll
        for (int q = 0; q < 8; q++) ag[q] += __shfl_xor(ag[q], m);
    }
    if (lane < 8) {
        float4 o0 = make_float4(ag[0] * inv, ag[1] * inv, ag[2] * inv, ag[3] * inv);
        float4 o1 = make_float4(ag[4] * inv, ag[5] * inv, ag[6] * inv, ag[7] * inv);
        A2g[(size_t)wv * 16 + s8 * 2 + 0] = o0;
        A2g[(size_t)wv * 16 + s8 * 2 + 1] = o1;
    }
}

// ---------------------------------------------------------------------------
// Layer-1 node kernel: h1 = relu([x|A1x|A1e] @ Wc1 + b1eff); g2(bf16) = h1@Wm2h
// ---------------------------------------------------------------------------
#define NPB1 16
__global__ __launch_bounds__(256) void node1_kernel(
    const float* __restrict__ x,
    const float* __restrict__ A1x,
    const float* __restrict__ A1e,
    const int*   __restrict__ deg,
    const float* __restrict__ Wc1,    // [160][128]
    const float* __restrict__ b1eff,  // [128]
    const float* __restrict__ bmW1,   // [128]
    const float* __restrict__ Wm2h,   // Wmsg2 rows 0..127 -> [128][64]
    float* __restrict__ h1,
    unsigned short* __restrict__ g2b,
    int N)
{
    __shared__ __align__(16) float sF[NPB1][160];   // [x | A1x | A1e]
    __shared__ __align__(16) float sH[NPB1][128];
    __shared__ float sCnt[NPB1];

    int t = threadIdx.x;              // 0..255
    int j = t & 127;                  // output column
    int g = t >> 7;                   // node group 0..1
    int base = blockIdx.x * NPB1;

    for (int q = t; q < NPB1 * 64; q += 256) {
        int n = q >> 6, k = q & 63;
        int v = base + n;
        sF[n][k]      = (v < N) ? x[(size_t)v * 64 + k]   : 0.f;
        sF[n][64 + k] = (v < N) ? A1x[(size_t)v * 64 + k] : 0.f;
    }
    for (int q = t; q < NPB1 * 32; q += 256) {
        int n = q >> 5, k = q & 31;
        int v = base + n;
        sF[n][128 + k] = (v < N) ? A1e[(size_t)v * 32 + k] : 0.f;
    }
    if (t < NPB1) {
        int v = base + t;
        sCnt[t] = (v < N) ? (float)deg[v] : 1.f;
    }
    __syncthreads();

    float acc[8];
#pragma unroll
    for (int n = 0; n < 8; n++) acc[n] = 0.f;

#pragma unroll 2
    for (int k = 0; k < 160; k += 4) {
        float w0 = Wc1[(k + 0) * 128 + j];
        float w1 = Wc1[(k + 1) * 128 + j];
        float w2 = Wc1[(k + 2) * 128 + j];
        float w3 = Wc1[(k + 3) * 128 + j];
#pragma unroll
        for (int n = 0; n < 8; n++) {
            const float4 f = *(const float4*)&sF[g * 8 + n][k];
            acc[n] = fmaf(f.x, w0, acc[n]);
            acc[n] = fmaf(f.y, w1, acc[n]);
            acc[n] = fmaf(f.z, w2, acc[n]);
            acc[n] = fmaf(f.w, w3, acc[n]);
        }
    }
    float b1 = b1eff[j];
    float bw = bmW1[j];
#pragma unroll
    for (int n = 0; n < 8; n++) {
        int v = base + g * 8 + n;
        float bias = (sCnt[g * 8 + n] > 0.f) ? b1 : (b1 - bw);
        float hv = fmaxf(acc[n] + bias, 0.f);
        sH[g * 8 + n][j] = hv;
        if (v < N) h1[(size_t)v * 128 + j] = hv;
    }
    __syncthreads();

    // g2 = sH @ Wm2h (128 -> 64): col=t&63, qg=t>>6 (0..3) -> 4 nodes each
    int col = t & 63;
    int qg = t >> 6;
    float ga[4];
#pragma unroll
    for (int n = 0; n < 4; n++) ga[n] = 0.f;
#pragma unroll 2
    for (int k = 0; k < 128; k += 4) {
        float w0 = Wm2h[(k + 0) * 64 + col];
        float w1 = Wm2h[(k + 1) * 64 + col];
        float w2 = Wm2h[(k + 2) * 64 + col];
        float w3 = Wm2h[(k + 3) * 64 + col];
#pragma unroll
        for (int n = 0; n < 4; n++) {
            const float4 f = *(const float4*)&sH[qg * 4 + n][k];
            ga[n] = fmaf(f.x, w0, ga[n]);
            ga[n] = fmaf(f.y, w1, ga[n]);
            ga[n] = fmaf(f.z, w2, ga[n]);
            ga[n] = fmaf(f.w, w3, ga[n]);
        }
    }
#pragma unroll
    for (int n = 0; n < 4; n++) {
        int v = base + qg * 4 + n;
        if (v < N) {
            unsigned int ub = __float_as_uint(ga[n]);
            ub += 0x7FFFu + ((ub >> 16) & 1u);
            g2b[(size_t)v * 64 + col] = (unsigned short)(ub >> 16);
        }
    }
}

// ---------------------------------------------------------------------------
// Layer-2 node kernel: out = relu([h1|A2g|A1e] @ Wc2 + b2eff)
// ---------------------------------------------------------------------------
#define NPB2 16
__global__ __launch_bounds__(256) void node2_kernel(
    const float* __restrict__ h1,
    const float* __restrict__ A2g,
    const float* __restrict__ A1e,
    const int*   __restrict__ deg,
    const float* __restrict__ Wc2,    // [224][64]
    const float* __restrict__ b2eff,  // [64]
    const float* __restrict__ bmW2,   // [64]
    float* __restrict__ out,
    int N)
{
    __shared__ __align__(16) float sF[NPB2][224];   // [h1 | A2g | A1e]
    __shared__ float sCnt[NPB2];

    int t = threadIdx.x;              // 0..255
    int j = t & 63;                   // output column
    int w = t >> 6;                   // node group 0..3
    int base = blockIdx.x * NPB2;

    for (int q = t; q < NPB2 * 128; q += 256) {
        int n = q >> 7, k = q & 127;
        int v = base + n;
        sF[n][k] = (v < N) ? h1[(size_t)v * 128 + k] : 0.f;
    }
    for (int q = t; q < NPB2 * 64; q += 256) {
        int n = q >> 6, k = q & 63;
        int v = base + n;
        sF[n][128 + k] = (v < N) ? A2g[(size_t)v * 64 + k] : 0.f;
    }
    for (int q = t; q < NPB2 * 32; q += 256) {
        int n = q >> 5, k = q & 31;
        int v = base + n;
        sF[n][192 + k] = (v < N) ? A1e[(size_t)v * 32 + k] : 0.f;
    }
    if (t < NPB2) {
        int v = base + t;
        sCnt[t] = (v < N) ? (float)deg[v] : 1.f;
    }
    __syncthreads();

    float acc[4];
#pragma unroll
    for (int n = 0; n < 4; n++) acc[n] = 0.f;

#pragma unroll 2
    for (int k = 0; k < 224; k += 4) {
        float w0 = Wc2[(k + 0) * 64 + j];
        float w1 = Wc2[(k + 1) * 64 + j];
        float w2 = Wc2[(k + 2) * 64 + j];
        float w3 = Wc2[(k + 3) * 64 + j];
#pragma unroll
        for (int n = 0; n < 4; n++) {
            const float4 f = *(const float4*)&sF[w * 4 + n][k];
            acc[n] = fmaf(f.x, w0, acc[n]);
            acc[n] = fmaf(f.y, w1, acc[n]);
            acc[n] = fmaf(f.z, w2, acc[n]);
            acc[n] = fmaf(f.w, w3, acc[n]);
        }
    }
    float b2 = b2eff[j];
    float bw = bmW2[j];
#pragma unroll
    for (int n = 0; n < 4; n++) {
        int v = base + w * 4 + n;
        float bias = (sCnt[w * 4 + n] > 0.f) ? b2 : (b2 - bw);
        if (v < N) out[(size_t)v * 64 + j] = fmaxf(acc[n] + bias, 0.f);
    }
}

// ---------------------------------------------------------------------------
extern "C" void kernel_launch(void* const* d_in, const int* in_sizes, int n_in,
                              void* d_out, int out_size, void* d_ws, size_t ws_size,
                              hipStream_t stream) {
    const float* x      = (const float*)d_in[0];
    const int*   ei     = (const int*)d_in[1];
    const float* ea     = (const float*)d_in[2];
    const float* Wmsg1  = (const float*)d_in[3];
    const float* bmsg1  = (const float*)d_in[4];
    const float* Wapp1  = (const float*)d_in[5];
    const float* bapp1  = (const float*)d_in[6];
    const float* Wmsg2  = (const float*)d_in[7];
    const float* bmsg2  = (const float*)d_in[8];
    const float* Wapp2  = (const float*)d_in[9];
    const float* bapp2  = (const float*)d_in[10];

    const int N = in_sizes[0] / 64;      // 50000
    const int E = in_sizes[1] / 2;       // 800000
    const int NCH = (N + SCAN_CHUNK - 1) / SCAN_CHUNK;
    const int* src = ei;
    const int* dst = ei + E;

    uint8_t* p = (uint8_t*)d_ws;
    auto alloc = [&](size_t bytes) -> void* {
        void* r = (void*)p;
        p += (bytes + 255) & ~(size_t)255;
        return r;
    };
    int*   deg    = (int*)alloc((size_t)N * 4);
    int*   off    = (int*)alloc((size_t)(N + 1) * 4);
    int*   cursor = (int*)alloc((size_t)N * 4);
    int*   part   = (int*)alloc((size_t)NCH * 4);
    int2*  elist  = (int2*)alloc((size_t)E * 8);
    float* A1x    = (float*)alloc((size_t)N * 64 * 4);  // reused as A2g
    float* A1e    = (float*)alloc((size_t)N * 32 * 4);
    float* h1     = (float*)alloc((size_t)N * 128 * 4);
    unsigned short* xb  = (unsigned short*)alloc((size_t)N * 64 * 2);
    unsigned short* g2b = (unsigned short*)alloc((size_t)N * 64 * 2);
    float* Wc1    = (float*)alloc(160 * 128 * 4);
    float* b1eff  = (float*)alloc(128 * 4);
    float* bmW1   = (float*)alloc(128 * 4);
    float* Wc2    = (float*)alloc(224 * 64 * 4);
    float* b2eff  = (float*)alloc(64 * 4);
    float* bmW2   = (float*)alloc(64 * 4);
    float* A2g    = A1x;   // safe: A1x consumed by node1 before agg2 writes A2g

    hipMemsetAsync(deg, 0, (size_t)N * 4, stream);

    // Weight composition + x conversion (independent of CSR build; tiny)
    compose1_kernel<<<161, 128, 0, stream>>>(Wmsg1, bmsg1, Wapp1, bapp1,
                                             Wc1, b1eff, bmW1);
    compose2_kernel<<<225, 64, 0, stream>>>(Wmsg2, bmsg2, Wapp2, bapp2,
                                            Wc2, b2eff, bmW2);
    {
        int n4 = N * 16;  // number of float4 in x
        cvt_x_kernel<<<(n4 + 255) / 256, 256, 0, stream>>>(
            (const float4*)x, (uint2*)xb, n4);
    }

    // CSR build
    hist_kernel<<<(E + 255) / 256, 256, 0, stream>>>(dst, deg, E);
    scanA_kernel<<<NCH, 256, 0, stream>>>(deg, part, N);
    scanB_kernel<<<1, 64, 0, stream>>>(part, off + N, NCH);
    scanC_kernel<<<NCH, SCAN_CHUNK, 0, stream>>>(deg, part, off, cursor, N);
    fill_kernel<<<(E + 255) / 256, 256, 0, stream>>>(src, dst, cursor, elist, E);

    // Layer 1
    agg1_kernel<<<(N + 3) / 4, 256, 0, stream>>>(
        (const uint4*)xb, (const float4*)ea, elist, off,
        (float4*)A1x, (float4*)A1e, N);
    node1_kernel<<<(N + NPB1 - 1) / NPB1, 256, 0, stream>>>(
        x, A1x, A1e, deg, Wc1, b1eff, bmW1, Wmsg2 /* rows 0..127 = Wm2h */,
        h1, g2b, N);

    // Layer 2
    agg2_kernel<<<(N + 3) / 4, 256, 0, stream>>>(
        (const uint4*)g2b, elist, off, (float4*)A2g, N);
    node2_kernel<<<(N + NPB2 - 1) / NPB2, 256, 0, stream>>>(
        h1, A2g, A1e, deg, Wc2, b2eff, bmW2,
        (float*)d_out, N);
}

// Round 8
// 214.605 us; speedup vs baseline: 11.4332x; 1.3189x over previous
//
#include <hip/hip_runtime.h>

#define SCAN_CHUNK 1024
#define NPB 32

typedef unsigned int   uint32;
typedef unsigned short ushort16;
typedef __attribute__((ext_vector_type(8))) short bf16x8;
typedef __attribute__((ext_vector_type(4))) float f32x4;
#define MFMA16(a,b,c) __builtin_amdgcn_mfma_f32_16x16x32_bf16(a,b,c,0,0,0)

__device__ inline float4 f4_xor_add(float4 v, int mask) {
    v.x += __shfl_xor(v.x, mask);
    v.y += __shfl_xor(v.y, mask);
    v.z += __shfl_xor(v.z, mask);
    v.w += __shfl_xor(v.w, mask);
    return v;
}

// bf16 helpers (RNE)
__device__ inline uint32 pack_bf16x2(float a, float b) {
    uint32 ua = __float_as_uint(a);
    uint32 ub = __float_as_uint(b);
    ua += 0x7FFFu + ((ua >> 16) & 1u);
    ub += 0x7FFFu + ((ub >> 16) & 1u);
    return (ua >> 16) | (ub & 0xFFFF0000u);
}
__device__ inline ushort16 bf16_1(float a) {
    uint32 u = __float_as_uint(a);
    u += 0x7FFFu + ((u >> 16) & 1u);
    return (ushort16)(u >> 16);
}
__device__ inline float bf_lo(uint32 u) { return __uint_as_float(u << 16); }
__device__ inline float bf_hi(uint32 u) { return __uint_as_float(u & 0xFFFF0000u); }

// ---------------------------------------------------------------------------
// x fp32 -> bf16
// ---------------------------------------------------------------------------
__global__ void cvt_x_kernel(const float4* __restrict__ xin,
                             uint2* __restrict__ xb, int n4)
{
    int i = blockIdx.x * blockDim.x + threadIdx.x;
    if (i < n4) {
        float4 v = xin[i];
        uint2 o;
        o.x = pack_bf16x2(v.x, v.y);
        o.y = pack_bf16x2(v.z, v.w);
        xb[i] = o;
    }
}

// ---------------------------------------------------------------------------
// CSR build
// ---------------------------------------------------------------------------
__global__ void hist_kernel(const int* __restrict__ dst, int* __restrict__ deg, int E)
{
    int e = blockIdx.x * blockDim.x + threadIdx.x;
    if (e < E) atomicAdd(&deg[dst[e]], 1);
}

__global__ __launch_bounds__(256) void scanA_kernel(const int* __restrict__ deg,
                                                    int* __restrict__ part, int N)
{
    __shared__ int red[256];
    int b = blockIdx.x, t = threadIdx.x;
    int base = b * SCAN_CHUNK;
    int s = 0;
    for (int i = t; i < SCAN_CHUNK; i += 256) {
        int idx = base + i;
        s += (idx < N) ? deg[idx] : 0;
    }
    red[t] = s;
    __syncthreads();
    for (int o = 128; o > 0; o >>= 1) {
        if (t < o) red[t] += red[t + o];
        __syncthreads();
    }
    if (t == 0) part[b] = red[0];
}

__global__ void scanB_kernel(int* __restrict__ part, int* __restrict__ offN, int NCH)
{
    int lane = threadIdx.x;
    int orig = (lane < NCH) ? part[lane] : 0;
    int v = orig;
    for (int s = 1; s < 64; s <<= 1) {
        int t = __shfl_up(v, s);
        if (lane >= s) v += t;
    }
    if (lane < NCH) part[lane] = v - orig;
    if (lane == NCH - 1) *offN = v;
}

__global__ __launch_bounds__(SCAN_CHUNK) void scanC_kernel(const int* __restrict__ deg,
                                                           const int* __restrict__ part,
                                                           int* __restrict__ off,
                                                           int* __restrict__ cursor, int N)
{
    __shared__ int buf[SCAN_CHUNK];
    int b = blockIdx.x, t = threadIdx.x;
    int idx = b * SCAN_CHUNK + t;
    int v = (idx < N) ? deg[idx] : 0;
    buf[t] = v;
    __syncthreads();
    for (int s = 1; s < SCAN_CHUNK; s <<= 1) {
        int tmp = (t >= s) ? buf[t - s] : 0;
        __syncthreads();
        buf[t] += tmp;
        __syncthreads();
    }
    int excl = buf[t] - v + part[b];
    if (idx < N) { off[idx] = excl; cursor[idx] = excl; }
}

__global__ void fill_kernel(const int* __restrict__ src, const int* __restrict__ dst,
                            int* __restrict__ cursor, int2* __restrict__ elist, int E)
{
    int e = blockIdx.x * blockDim.x + threadIdx.x;
    if (e >= E) return;
    int d = dst[e];
    int p = atomicAdd(&cursor[d], 1);
    elist[p] = make_int2(src[e], e);
}

// ---------------------------------------------------------------------------
// Weight composition (layer 1) -> transposed bf16 Wc1T[128][160]
// rows(k) 0-63 = Wapp1_top; 64-159 = Wmsg1 @ Wapp1_bot
// ---------------------------------------------------------------------------
__global__ __launch_bounds__(128) void compose1_kernel(
    const float* __restrict__ Wmsg1, const float* __restrict__ bmsg1,
    const float* __restrict__ Wapp1, const float* __restrict__ bapp1,
    ushort16* __restrict__ Wc1T, float* __restrict__ b1eff, float* __restrict__ bmW1)
{
    int b = blockIdx.x;   // k-row 0..160
    int j = threadIdx.x;  // 0..127
    if (b < 64) {
        Wc1T[(size_t)j * 160 + b] = bf16_1(Wapp1[b * 128 + j]);
    } else if (b < 160) {
        int ar = b - 64;
        float s = 0.f;
        for (int k = 0; k < 128; k++)
            s = fmaf(Wmsg1[ar * 128 + k], Wapp1[(64 + k) * 128 + j], s);
        Wc1T[(size_t)j * 160 + b] = bf16_1(s);
    } else {
        float s = 0.f;
        for (int k = 0; k < 128; k++)
            s = fmaf(bmsg1[k], Wapp1[(64 + k) * 128 + j], s);
        bmW1[j] = s;
        b1eff[j] = bapp1[j] + s;
    }
}

// ---------------------------------------------------------------------------
// Weight composition (layer 2) -> transposed bf16 Wc2T[64][224]
// rows(k) 0-191 = Wapp2; 192-223 = Wmsg2_ea @ Wapp2_bot
// ---------------------------------------------------------------------------
__global__ __launch_bounds__(64) void compose2_kernel(
    const float* __restrict__ Wmsg2, const float* __restrict__ bmsg2,
    const float* __restrict__ Wapp2, const float* __restrict__ bapp2,
    ushort16* __restrict__ Wc2T, float* __restrict__ b2eff, float* __restrict__ bmW2)
{
    int b = blockIdx.x;  // 0..224
    int j = threadIdx.x; // 0..63
    if (b < 192) {
        Wc2T[(size_t)j * 224 + b] = bf16_1(Wapp2[b * 64 + j]);
    } else if (b < 224) {
        int ar = 128 + (b - 192);
        float s = 0.f;
        for (int k = 0; k < 64; k++)
            s = fmaf(Wmsg2[ar * 64 + k], Wapp2[(128 + k) * 64 + j], s);
        Wc2T[(size_t)j * 224 + b] = bf16_1(s);
    } else {
        float s = 0.f;
        for (int k = 0; k < 64; k++)
            s = fmaf(bmsg2[k], Wapp2[(128 + k) * 64 + j], s);
        bmW2[j] = s;
        b2eff[j] = bapp2[j] + s;
    }
}

// Wm2hT[64][128] bf16 = transpose of Wmsg2 rows 0..127
__global__ __launch_bounds__(64) void composem_kernel(
    const float* __restrict__ Wmsg2, ushort16* __restrict__ Wm2hT)
{
    int k = blockIdx.x;   // 0..127
    int c = threadIdx.x;  // 0..63
    Wm2hT[(size_t)c * 128 + k] = bf16_1(Wmsg2[k * 64 + c]);
}

// ---------------------------------------------------------------------------
// Layer-1 aggregate (unchanged from R7)
// ---------------------------------------------------------------------------
__global__ __launch_bounds__(256) void agg1_kernel(const uint4* __restrict__ xb,
                                                   const float4* __restrict__ ea4,
                                                   const int2* __restrict__ elist,
                                                   const int* __restrict__ off,
                                                   float4* __restrict__ A1x,
                                                   float4* __restrict__ A1e, int N)
{
    int wv = (blockIdx.x * blockDim.x + threadIdx.x) >> 6;
    int lane = threadIdx.x & 63;
    if (wv >= N) return;
    int beg = off[wv], end = off[wv + 1];
    float inv = 1.0f / fmaxf((float)(end - beg), 1.0f);

    int g8 = lane >> 3, s8 = lane & 7;

    float ax[8];
#pragma unroll
    for (int q = 0; q < 8; q++) ax[q] = 0.f;
    for (int i = beg + g8; i < end; i += 8) {
        int row = elist[i].x;
        uint4 v = xb[(size_t)row * 8 + s8];
        ax[0] += bf_lo(v.x); ax[1] += bf_hi(v.x);
        ax[2] += bf_lo(v.y); ax[3] += bf_hi(v.y);
        ax[4] += bf_lo(v.z); ax[5] += bf_hi(v.z);
        ax[6] += bf_lo(v.w); ax[7] += bf_hi(v.w);
    }
#pragma unroll
    for (int m = 8; m <= 32; m <<= 1) {
#pragma unroll
        for (int q = 0; q < 8; q++) ax[q] += __shfl_xor(ax[q], m);
    }
    if (lane < 8) {
        float4 o0 = make_float4(ax[0] * inv, ax[1] * inv, ax[2] * inv, ax[3] * inv);
        float4 o1 = make_float4(ax[4] * inv, ax[5] * inv, ax[6] * inv, ax[7] * inv);
        A1x[(size_t)wv * 16 + s8 * 2 + 0] = o0;
        A1x[(size_t)wv * 16 + s8 * 2 + 1] = o1;
    }

    float4 ae = make_float4(0.f, 0.f, 0.f, 0.f);
    for (int i = beg + g8; i < end; i += 8) {
        int eid = elist[i].y;
        float4 v = ea4[(size_t)eid * 8 + s8];
        ae.x += v.x; ae.y += v.y; ae.z += v.z; ae.w += v.w;
    }
    ae = f4_xor_add(ae, 8);
    ae = f4_xor_add(ae, 16);
    ae = f4_xor_add(ae, 32);
    if (lane < 8) {
        ae.x *= inv; ae.y *= inv; ae.z *= inv; ae.w *= inv;
        A1e[(size_t)wv * 8 + s8] = ae;
    }
}

// ---------------------------------------------------------------------------
// Layer-2 aggregate (unchanged from R7; reads bf16 g2)
// ---------------------------------------------------------------------------
__global__ __launch_bounds__(256) void agg2_kernel(const uint4* __restrict__ g2b,
                                                   const int2* __restrict__ elist,
                                                   const int* __restrict__ off,
                                                   float4* __restrict__ A2g, int N)
{
    int wv = (blockIdx.x * blockDim.x + threadIdx.x) >> 6;
    int lane = threadIdx.x & 63;
    if (wv >= N) return;
    int beg = off[wv], end = off[wv + 1];
    float inv = 1.0f / fmaxf((float)(end - beg), 1.0f);

    int g8 = lane >> 3, s8 = lane & 7;
    float ag[8];
#pragma unroll
    for (int q = 0; q < 8; q++) ag[q] = 0.f;
    for (int i = beg + g8; i < end; i += 8) {
        int row = elist[i].x;
        uint4 v = g2b[(size_t)row * 8 + s8];
        ag[0] += bf_lo(v.x); ag[1] += bf_hi(v.x);
        ag[2] += bf_lo(v.y); ag[3] += bf_hi(v.y);
        ag[4] += bf_lo(v.z); ag[5] += bf_hi(v.z);
        ag[6] += bf_lo(v.w); ag[7] += bf_hi(v.w);
    }
#pragma unroll
    for (int m = 8; m <= 32; m <<= 1) {
#pragma unroll
        for (int q = 0; q < 8; q++) ag[q] += __shfl_xor(ag[q], m);
    }
    if (lane < 8) {
        float4 o0 = make_float4(ag[0] * inv, ag[1] * inv, ag[2] * inv, ag[3] * inv);
        float4 o1 = make_float4(ag[4] * inv, ag[5] * inv, ag[6] * inv, ag[7] * inv);
        A2g[(size_t)wv * 16 + s8 * 2 + 0] = o0;
        A2g[(size_t)wv * 16 + s8 * 2 + 1] = o1;
    }
}

// ---------------------------------------------------------------------------
// Layer-1 node kernel (MFMA): 32 nodes/block, 512 threads (8 waves).
// GEMM1: F[32][160] @ Wc1T -> h (bias+relu) ; GEMM2: h[32][128] @ Wm2hT -> g2
// LDS rows padded to 336B (bank-spread for A-frag ds_read_b128).
// ---------------------------------------------------------------------------
__global__ __launch_bounds__(512) void node1_kernel(
    const uint32* __restrict__ xb,     // [N][32] dwords (bf16x2)
    const float* __restrict__ A1x,     // [N][64] f32
    const float* __restrict__ A1e,     // [N][32] f32
    const int*   __restrict__ deg,
    const ushort16* __restrict__ Wc1T, // [128][160] bf16
    const float* __restrict__ b1eff,
    const float* __restrict__ bmW1,
    const ushort16* __restrict__ Wm2hT,// [64][128] bf16
    uint32* __restrict__ h1b,          // [N][64] dwords (bf16x2)
    uint32* __restrict__ g2b,          // [N][32] dwords (bf16x2)
    int N)
{
    __shared__ ushort16 sFb[NPB][168];  // 160 used, 336B stride
    __shared__ ushort16 sHb[NPB][168];  // 128 used
    __shared__ float sCnt[NPB];

    int t = threadIdx.x;
    int base = blockIdx.x * NPB;
    int tr = t >> 4, c16 = t & 15;
    int v = base + tr;
    bool vok = v < N;

    // stage F = [x(bf16) | A1x | A1e] as bf16, 80 dwords/row
    uint32* sFrow = (uint32*)&sFb[tr][0];
#pragma unroll
    for (int m = 0; m < 5; m++) {
        int d = c16 + 16 * m;
        uint32 w = 0;
        if (vok) {
            if (d < 32) {
                w = xb[(size_t)v * 32 + d];
            } else if (d < 64) {
                int o = (d - 32) * 2;
                w = pack_bf16x2(A1x[(size_t)v * 64 + o], A1x[(size_t)v * 64 + o + 1]);
            } else {
                int o = (d - 64) * 2;
                w = pack_bf16x2(A1e[(size_t)v * 32 + o], A1e[(size_t)v * 32 + o + 1]);
            }
        }
        sFrow[d] = w;
    }
    if (t < NPB) sCnt[t] = (base + t < N) ? (float)deg[base + t] : 1.f;
    __syncthreads();

    int lane = t & 63;
    int wv = t >> 6;          // wave 0..7 = col-tile for GEMM1
    int lr = lane & 15;
    int kg = lane >> 4;       // k-group 0..3

    // GEMM1: 2 row-tiles x 1 col-tile per wave, K=160 (5 steps)
    f32x4 acc0 = {0.f, 0.f, 0.f, 0.f};
    f32x4 acc1 = {0.f, 0.f, 0.f, 0.f};
    const ushort16* bp1 = &Wc1T[(size_t)(wv * 16 + lr) * 160 + kg * 8];
#pragma unroll
    for (int kt = 0; kt < 5; kt++) {
        bf16x8 a0 = *(const bf16x8*)&sFb[lr][kt * 32 + kg * 8];
        bf16x8 a1 = *(const bf16x8*)&sFb[16 + lr][kt * 32 + kg * 8];
        bf16x8 b  = *(const bf16x8*)&bp1[kt * 32];
        acc0 = MFMA16(a0, b, acc0);
        acc1 = MFMA16(a1, b, acc1);
    }
    int col = wv * 16 + lr;
    float bj = b1eff[col], bw = bmW1[col];
    // epilogue: bias+relu, pack col-pairs via shfl, write sHb (bf16)
#pragma unroll
    for (int rt = 0; rt < 2; rt++) {
        f32x4 acc = rt ? acc1 : acc0;
        int r0 = rt * 16 + kg * 4;
#pragma unroll
        for (int reg = 0; reg < 4; reg++) {
            float c = sCnt[r0 + reg];
            float hv = fmaxf(acc[reg] + (c > 0.f ? bj : bj - bw), 0.f);
            float other = __shfl_xor(hv, 1);
            if (!(lane & 1))
                ((uint32*)&sHb[r0 + reg][0])[col >> 1] = pack_bf16x2(hv, other);
        }
    }
    __syncthreads();

    // write h1b (coalesced, 64 dwords/row)
#pragma unroll
    for (int m = 0; m < 4; m++) {
        int d = c16 + 16 * m;
        if (vok) h1b[(size_t)v * 64 + d] = ((uint32*)&sHb[tr][0])[d];
    }

    // GEMM2: g2 = h @ Wm2hT, tiles: rt2 = wv>>2, ct2 = wv&3, K=128 (4 steps)
    int rt2 = wv >> 2, ct2 = wv & 3;
    f32x4 accg = {0.f, 0.f, 0.f, 0.f};
    const ushort16* bp2 = &Wm2hT[(size_t)(ct2 * 16 + lr) * 128 + kg * 8];
#pragma unroll
    for (int kt = 0; kt < 4; kt++) {
        bf16x8 a = *(const bf16x8*)&sHb[rt2 * 16 + lr][kt * 32 + kg * 8];
        bf16x8 b = *(const bf16x8*)&bp2[kt * 32];
        accg = MFMA16(a, b, accg);
    }
    int colg = ct2 * 16 + lr;
    int rg0 = rt2 * 16 + kg * 4;
#pragma unroll
    for (int reg = 0; reg < 4; reg++) {
        float other = __shfl_xor(accg[reg], 1);
        int vr = base + rg0 + reg;
        if (!(lane & 1) && vr < N)
            g2b[(size_t)vr * 32 + (colg >> 1)] = pack_bf16x2(accg[reg], other);
    }
}

// ---------------------------------------------------------------------------
// Layer-2 node kernel (MFMA): out = relu([h1|A2g|A1e] @ Wc2T + bias)
// 32 nodes/block, 512 threads; K=224 (7 steps); 8 output tiles, 1 per wave.
// ---------------------------------------------------------------------------
__global__ __launch_bounds__(512) void node2_kernel(
    const uint32* __restrict__ h1b,    // [N][64] dwords
    const float* __restrict__ A2g,     // [N][64] f32
    const float* __restrict__ A1e,     // [N][32] f32
    const int*   __restrict__ deg,
    const ushort16* __restrict__ Wc2T, // [64][224] bf16
    const float* __restrict__ b2eff,
    const float* __restrict__ bmW2,
    float* __restrict__ out,
    int N)
{
    __shared__ ushort16 sFb[NPB][232];  // 224 used, 464B stride
    __shared__ float sCnt[NPB];

    int t = threadIdx.x;
    int base = blockIdx.x * NPB;
    int tr = t >> 4, c16 = t & 15;
    int v = base + tr;
    bool vok = v < N;

    uint32* sFrow = (uint32*)&sFb[tr][0];
#pragma unroll
    for (int m = 0; m < 7; m++) {
        int d = c16 + 16 * m;   // 0..111
        uint32 w = 0;
        if (vok) {
            if (d < 64) {
                w = h1b[(size_t)v * 64 + d];
            } else if (d < 96) {
                int o = (d - 64) * 2;
                w = pack_bf16x2(A2g[(size_t)v * 64 + o], A2g[(size_t)v * 64 + o + 1]);
            } else {
                int o = (d - 96) * 2;
                w = pack_bf16x2(A1e[(size_t)v * 32 + o], A1e[(size_t)v * 32 + o + 1]);
            }
        }
        sFrow[d] = w;
    }
    if (t < NPB) sCnt[t] = (base + t < N) ? (float)deg[base + t] : 1.f;
    __syncthreads();

    int lane = t & 63;
    int wv = t >> 6;
    int lr = lane & 15;
    int kg = lane >> 4;
    int rt = wv >> 2, ct = wv & 3;

    f32x4 acc = {0.f, 0.f, 0.f, 0.f};
    const ushort16* bp = &Wc2T[(size_t)(ct * 16 + lr) * 224 + kg * 8];
#pragma unroll
    for (int kt = 0; kt < 7; kt++) {
        bf16x8 a = *(const bf16x8*)&sFb[rt * 16 + lr][kt * 32 + kg * 8];
        bf16x8 b = *(const bf16x8*)&bp[kt * 32];
        acc = MFMA16(a, b, acc);
    }
    int col = ct * 16 + lr;
    float bj = b2eff[col], bw = bmW2[col];
    int r0 = rt * 16 + kg * 4;
#pragma unroll
    for (int reg = 0; reg < 4; reg++) {
        int vr = base + r0 + reg;
        float c = sCnt[r0 + reg];
        float bias = (c > 0.f) ? bj : bj - bw;
        if (vr < N) out[(size_t)vr * 64 + col] = fmaxf(acc[reg] + bias, 0.f);
    }
}

// ---------------------------------------------------------------------------
extern "C" void kernel_launch(void* const* d_in, const int* in_sizes, int n_in,
                              void* d_out, int out_size, void* d_ws, size_t ws_size,
                              hipStream_t stream) {
    const float* x      = (const float*)d_in[0];
    const int*   ei     = (const int*)d_in[1];
    const float* ea     = (const float*)d_in[2];
    const float* Wmsg1  = (const float*)d_in[3];
    const float* bmsg1  = (const float*)d_in[4];
    const float* Wapp1  = (const float*)d_in[5];
    const float* bapp1  = (const float*)d_in[6];
    const float* Wmsg2  = (const float*)d_in[7];
    const float* bmsg2  = (const float*)d_in[8];
    const float* Wapp2  = (const float*)d_in[9];
    const float* bapp2  = (const float*)d_in[10];

    const int N = in_sizes[0] / 64;      // 50000
    const int E = in_sizes[1] / 2;       // 800000
    const int NCH = (N + SCAN_CHUNK - 1) / SCAN_CHUNK;
    const int* src = ei;
    const int* dst = ei + E;

    uint8_t* p = (uint8_t*)d_ws;
    auto alloc = [&](size_t bytes) -> void* {
        void* r = (void*)p;
        p += (bytes + 255) & ~(size_t)255;
        return r;
    };
    int*     deg    = (int*)alloc((size_t)N * 4);
    int*     off    = (int*)alloc((size_t)(N + 1) * 4);
    int*     cursor = (int*)alloc((size_t)N * 4);
    int*     part   = (int*)alloc((size_t)NCH * 4);
    int2*    elist  = (int2*)alloc((size_t)E * 8);
    float*   A1x    = (float*)alloc((size_t)N * 64 * 4);  // reused as A2g
    float*   A1e    = (float*)alloc((size_t)N * 32 * 4);
    uint32*  xb     = (uint32*)alloc((size_t)N * 32 * 4);
    uint32*  h1b    = (uint32*)alloc((size_t)N * 64 * 4);
    uint32*  g2b    = (uint32*)alloc((size_t)N * 32 * 4);
    ushort16* Wc1T  = (ushort16*)alloc(128 * 160 * 2);
    ushort16* Wc2T  = (ushort16*)alloc(64 * 224 * 2);
    ushort16* Wm2hT = (ushort16*)alloc(64 * 128 * 2);
    float*   b1eff  = (float*)alloc(128 * 4);
    float*   bmW1   = (float*)alloc(128 * 4);
    float*   b2eff  = (float*)alloc(64 * 4);
    float*   bmW2   = (float*)alloc(64 * 4);
    float*   A2g    = A1x;   // safe: A1x consumed by node1 before agg2 writes A2g

    hipMemsetAsync(deg, 0, (size_t)N * 4, stream);

    // Weight composition + x conversion
    compose1_kernel<<<161, 128, 0, stream>>>(Wmsg1, bmsg1, Wapp1, bapp1,
                                             Wc1T, b1eff, bmW1);
    compose2_kernel<<<225, 64, 0, stream>>>(Wmsg2, bmsg2, Wapp2, bapp2,
                                            Wc2T, b2eff, bmW2);
    composem_kernel<<<128, 64, 0, stream>>>(Wmsg2, Wm2hT);
    {
        int n4 = N * 16;
        cvt_x_kernel<<<(n4 + 255) / 256, 256, 0, stream>>>(
            (const float4*)x, (uint2*)xb, n4);
    }

    // CSR build
    hist_kernel<<<(E + 255) / 256, 256, 0, stream>>>(dst, deg, E);
    scanA_kernel<<<NCH, 256, 0, stream>>>(deg, part, N);
    scanB_kernel<<<1, 64, 0, stream>>>(part, off + N, NCH);
    scanC_kernel<<<NCH, SCAN_CHUNK, 0, stream>>>(deg, part, off, cursor, N);
    fill_kernel<<<(E + 255) / 256, 256, 0, stream>>>(src, dst, cursor, elist, E);

    // Layer 1
    agg1_kernel<<<(N + 3) / 4, 256, 0, stream>>>(
        (const uint4*)xb, (const float4*)ea, elist, off,
        (float4*)A1x, (float4*)A1e, N);
    node1_kernel<<<(N + NPB - 1) / NPB, 512, 0, stream>>>(
        xb, A1x, A1e, deg, Wc1T, b1eff, bmW1, Wm2hT, h1b, g2b, N);

    // Layer 2
    agg2_kernel<<<(N + 3) / 4, 256, 0, stream>>>(
        (const uint4*)g2b, elist, off, (float4*)A2g, N);
    node2_kernel<<<(N + NPB - 1) / NPB, 512, 0, stream>>>(
        h1b, A2g, A1e, deg, Wc2T, b2eff, bmW2,
        (float*)d_out, N);
}

// Round 9
// 212.242 us; speedup vs baseline: 11.5605x; 1.0111x over previous
//
#include <hip/hip_runtime.h>

#define SCAN_CHUNK 1024
#define NPB 32

typedef unsigned int   uint32;
typedef unsigned short ushort16;
typedef __attribute__((ext_vector_type(8))) short bf16x8;
typedef __attribute__((ext_vector_type(4))) float f32x4;
#define MFMA16(a,b,c) __builtin_amdgcn_mfma_f32_16x16x32_bf16(a,b,c,0,0,0)

// bf16 helpers (RNE)
__device__ inline uint32 pack_bf16x2(float a, float b) {
    uint32 ua = __float_as_uint(a);
    uint32 ub = __float_as_uint(b);
    ua += 0x7FFFu + ((ua >> 16) & 1u);
    ub += 0x7FFFu + ((ub >> 16) & 1u);
    return (ua >> 16) | (ub & 0xFFFF0000u);
}
__device__ inline ushort16 bf16_1(float a) {
    uint32 u = __float_as_uint(a);
    u += 0x7FFFu + ((u >> 16) & 1u);
    return (ushort16)(u >> 16);
}
__device__ inline float bf_lo(uint32 u) { return __uint_as_float(u << 16); }
__device__ inline float bf_hi(uint32 u) { return __uint_as_float(u & 0xFFFF0000u); }

// ---------------------------------------------------------------------------
// x fp32 -> bf16
// ---------------------------------------------------------------------------
__global__ void cvt_x_kernel(const float4* __restrict__ xin,
                             uint2* __restrict__ xb, int n4)
{
    int i = blockIdx.x * blockDim.x + threadIdx.x;
    if (i < n4) {
        float4 v = xin[i];
        uint2 o;
        o.x = pack_bf16x2(v.x, v.y);
        o.y = pack_bf16x2(v.z, v.w);
        xb[i] = o;
    }
}

// ---------------------------------------------------------------------------
// CSR build
// ---------------------------------------------------------------------------
__global__ void hist_kernel(const int* __restrict__ dst, int* __restrict__ deg, int E)
{
    int e = blockIdx.x * blockDim.x + threadIdx.x;
    if (e < E) atomicAdd(&deg[dst[e]], 1);
}

__global__ __launch_bounds__(256) void scanA_kernel(const int* __restrict__ deg,
                                                    int* __restrict__ part, int N)
{
    __shared__ int red[256];
    int b = blockIdx.x, t = threadIdx.x;
    int base = b * SCAN_CHUNK;
    int s = 0;
    for (int i = t; i < SCAN_CHUNK; i += 256) {
        int idx = base + i;
        s += (idx < N) ? deg[idx] : 0;
    }
    red[t] = s;
    __syncthreads();
    for (int o = 128; o > 0; o >>= 1) {
        if (t < o) red[t] += red[t + o];
        __syncthreads();
    }
    if (t == 0) part[b] = red[0];
}

__global__ void scanB_kernel(int* __restrict__ part, int* __restrict__ offN, int NCH)
{
    int lane = threadIdx.x;
    int orig = (lane < NCH) ? part[lane] : 0;
    int v = orig;
    for (int s = 1; s < 64; s <<= 1) {
        int t = __shfl_up(v, s);
        if (lane >= s) v += t;
    }
    if (lane < NCH) part[lane] = v - orig;
    if (lane == NCH - 1) *offN = v;
}

__global__ __launch_bounds__(SCAN_CHUNK) void scanC_kernel(const int* __restrict__ deg,
                                                           const int* __restrict__ part,
                                                           int* __restrict__ off,
                                                           int* __restrict__ cursor, int N)
{
    __shared__ int buf[SCAN_CHUNK];
    int b = blockIdx.x, t = threadIdx.x;
    int idx = b * SCAN_CHUNK + t;
    int v = (idx < N) ? deg[idx] : 0;
    buf[t] = v;
    __syncthreads();
    for (int s = 1; s < SCAN_CHUNK; s <<= 1) {
        int tmp = (t >= s) ? buf[t - s] : 0;
        __syncthreads();
        buf[t] += tmp;
        __syncthreads();
    }
    int excl = buf[t] - v + part[b];
    if (idx < N) { off[idx] = excl; cursor[idx] = excl; }
}

__global__ void fill_kernel(const int* __restrict__ src, const int* __restrict__ dst,
                            int* __restrict__ cursor, int2* __restrict__ elist, int E)
{
    int e = blockIdx.x * blockDim.x + threadIdx.x;
    if (e >= E) return;
    int d = dst[e];
    int p = atomicAdd(&cursor[d], 1);
    elist[p] = make_int2(src[e], e);
}

// ---------------------------------------------------------------------------
// Weight composition (layer 1) -> transposed bf16 Wc1T[128][160]
// ---------------------------------------------------------------------------
__global__ __launch_bounds__(128) void compose1_kernel(
    const float* __restrict__ Wmsg1, const float* __restrict__ bmsg1,
    const float* __restrict__ Wapp1, const float* __restrict__ bapp1,
    ushort16* __restrict__ Wc1T, float* __restrict__ b1eff, float* __restrict__ bmW1)
{
    int b = blockIdx.x;   // k-row 0..160
    int j = threadIdx.x;  // 0..127
    if (b < 64) {
        Wc1T[(size_t)j * 160 + b] = bf16_1(Wapp1[b * 128 + j]);
    } else if (b < 160) {
        int ar = b - 64;
        float s = 0.f;
        for (int k = 0; k < 128; k++)
            s = fmaf(Wmsg1[ar * 128 + k], Wapp1[(64 + k) * 128 + j], s);
        Wc1T[(size_t)j * 160 + b] = bf16_1(s);
    } else {
        float s = 0.f;
        for (int k = 0; k < 128; k++)
            s = fmaf(bmsg1[k], Wapp1[(64 + k) * 128 + j], s);
        bmW1[j] = s;
        b1eff[j] = bapp1[j] + s;
    }
}

// ---------------------------------------------------------------------------
// Weight composition (layer 2) -> transposed bf16 Wc2T[64][224]
// ---------------------------------------------------------------------------
__global__ __launch_bounds__(64) void compose2_kernel(
    const float* __restrict__ Wmsg2, const float* __restrict__ bmsg2,
    const float* __restrict__ Wapp2, const float* __restrict__ bapp2,
    ushort16* __restrict__ Wc2T, float* __restrict__ b2eff, float* __restrict__ bmW2)
{
    int b = blockIdx.x;  // 0..224
    int j = threadIdx.x; // 0..63
    if (b < 192) {
        Wc2T[(size_t)j * 224 + b] = bf16_1(Wapp2[b * 64 + j]);
    } else if (b < 224) {
        int ar = 128 + (b - 192);
        float s = 0.f;
        for (int k = 0; k < 64; k++)
            s = fmaf(Wmsg2[ar * 64 + k], Wapp2[(128 + k) * 64 + j], s);
        Wc2T[(size_t)j * 224 + b] = bf16_1(s);
    } else {
        float s = 0.f;
        for (int k = 0; k < 64; k++)
            s = fmaf(bmsg2[k], Wapp2[(128 + k) * 64 + j], s);
        bmW2[j] = s;
        b2eff[j] = bapp2[j] + s;
    }
}

// Wm2hT[64][128] bf16 = transpose of Wmsg2 rows 0..127
__global__ __launch_bounds__(64) void composem_kernel(
    const float* __restrict__ Wmsg2, ushort16* __restrict__ Wm2hT)
{
    int k = blockIdx.x;   // 0..127
    int c = threadIdx.x;  // 0..63
    Wm2hT[(size_t)c * 128 + k] = bf16_1(Wmsg2[k * 64 + c]);
}

// ---------------------------------------------------------------------------
// Layer-1 aggregate: 8 nodes/wave, one 8-lane group per node, no shuffles.
// Lane s8 owns 16B chunk s8 of both the x row (uint4 bf16) and ea row (float4).
// ---------------------------------------------------------------------------
__global__ __launch_bounds__(256) void agg1_kernel(const uint4* __restrict__ xb,
                                                   const float4* __restrict__ ea4,
                                                   const int2* __restrict__ elist,
                                                   const int* __restrict__ off,
                                                   float4* __restrict__ A1x,
                                                   float4* __restrict__ A1e, int N)
{
    int tid = blockIdx.x * blockDim.x + threadIdx.x;
    int node = tid >> 3;          // 8 lanes per node
    int s8 = tid & 7;
    if (node >= N) return;
    int beg = off[node], end = off[node + 1];
    float inv = 1.0f / fmaxf((float)(end - beg), 1.0f);

    float ax[8];
#pragma unroll
    for (int q = 0; q < 8; q++) ax[q] = 0.f;
    float4 ae = make_float4(0.f, 0.f, 0.f, 0.f);

    for (int i = beg; i < end; i++) {
        int2 pr = elist[i];
        uint4 vx = xb[(size_t)pr.x * 8 + s8];
        float4 ve = ea4[(size_t)pr.y * 8 + s8];
        ax[0] += bf_lo(vx.x); ax[1] += bf_hi(vx.x);
        ax[2] += bf_lo(vx.y); ax[3] += bf_hi(vx.y);
        ax[4] += bf_lo(vx.z); ax[5] += bf_hi(vx.z);
        ax[6] += bf_lo(vx.w); ax[7] += bf_hi(vx.w);
        ae.x += ve.x; ae.y += ve.y; ae.z += ve.z; ae.w += ve.w;
    }
    float4 o0 = make_float4(ax[0] * inv, ax[1] * inv, ax[2] * inv, ax[3] * inv);
    float4 o1 = make_float4(ax[4] * inv, ax[5] * inv, ax[6] * inv, ax[7] * inv);
    A1x[(size_t)node * 16 + s8 * 2 + 0] = o0;
    A1x[(size_t)node * 16 + s8 * 2 + 1] = o1;
    ae.x *= inv; ae.y *= inv; ae.z *= inv; ae.w *= inv;
    A1e[(size_t)node * 8 + s8] = ae;
}

// ---------------------------------------------------------------------------
// Layer-2 aggregate: same structure; g2 row = 8 x uint4 (bf16).
// ---------------------------------------------------------------------------
__global__ __launch_bounds__(256) void agg2_kernel(const uint4* __restrict__ g2b,
                                                   const int2* __restrict__ elist,
                                                   const int* __restrict__ off,
                                                   float4* __restrict__ A2g, int N)
{
    int tid = blockIdx.x * blockDim.x + threadIdx.x;
    int node = tid >> 3;
    int s8 = tid & 7;
    if (node >= N) return;
    int beg = off[node], end = off[node + 1];
    float inv = 1.0f / fmaxf((float)(end - beg), 1.0f);

    float ag[8];
#pragma unroll
    for (int q = 0; q < 8; q++) ag[q] = 0.f;

    for (int i = beg; i < end; i++) {
        int row = elist[i].x;
        uint4 v = g2b[(size_t)row * 8 + s8];
        ag[0] += bf_lo(v.x); ag[1] += bf_hi(v.x);
        ag[2] += bf_lo(v.y); ag[3] += bf_hi(v.y);
        ag[4] += bf_lo(v.z); ag[5] += bf_hi(v.z);
        ag[6] += bf_lo(v.w); ag[7] += bf_hi(v.w);
    }
    float4 o0 = make_float4(ag[0] * inv, ag[1] * inv, ag[2] * inv, ag[3] * inv);
    float4 o1 = make_float4(ag[4] * inv, ag[5] * inv, ag[6] * inv, ag[7] * inv);
    A2g[(size_t)node * 16 + s8 * 2 + 0] = o0;
    A2g[(size_t)node * 16 + s8 * 2 + 1] = o1;
}

// ---------------------------------------------------------------------------
// Layer-1 node kernel (MFMA) — unchanged from R8
// ---------------------------------------------------------------------------
__global__ __launch_bounds__(512) void node1_kernel(
    const uint32* __restrict__ xb,     // [N][32] dwords (bf16x2)
    const float* __restrict__ A1x,     // [N][64] f32
    const float* __restrict__ A1e,     // [N][32] f32
    const int*   __restrict__ deg,
    const ushort16* __restrict__ Wc1T, // [128][160] bf16
    const float* __restrict__ b1eff,
    const float* __restrict__ bmW1,
    const ushort16* __restrict__ Wm2hT,// [64][128] bf16
    uint32* __restrict__ h1b,          // [N][64] dwords (bf16x2)
    uint32* __restrict__ g2b,          // [N][32] dwords (bf16x2)
    int N)
{
    __shared__ ushort16 sFb[NPB][168];  // 160 used, 336B stride
    __shared__ ushort16 sHb[NPB][168];  // 128 used
    __shared__ float sCnt[NPB];

    int t = threadIdx.x;
    int base = blockIdx.x * NPB;
    int tr = t >> 4, c16 = t & 15;
    int v = base + tr;
    bool vok = v < N;

    uint32* sFrow = (uint32*)&sFb[tr][0];
#pragma unroll
    for (int m = 0; m < 5; m++) {
        int d = c16 + 16 * m;
        uint32 w = 0;
        if (vok) {
            if (d < 32) {
                w = xb[(size_t)v * 32 + d];
            } else if (d < 64) {
                int o = (d - 32) * 2;
                w = pack_bf16x2(A1x[(size_t)v * 64 + o], A1x[(size_t)v * 64 + o + 1]);
            } else {
                int o = (d - 64) * 2;
                w = pack_bf16x2(A1e[(size_t)v * 32 + o], A1e[(size_t)v * 32 + o + 1]);
            }
        }
        sFrow[d] = w;
    }
    if (t < NPB) sCnt[t] = (base + t < N) ? (float)deg[base + t] : 1.f;
    __syncthreads();

    int lane = t & 63;
    int wv = t >> 6;
    int lr = lane & 15;
    int kg = lane >> 4;

    f32x4 acc0 = {0.f, 0.f, 0.f, 0.f};
    f32x4 acc1 = {0.f, 0.f, 0.f, 0.f};
    const ushort16* bp1 = &Wc1T[(size_t)(wv * 16 + lr) * 160 + kg * 8];
#pragma unroll
    for (int kt = 0; kt < 5; kt++) {
        bf16x8 a0 = *(const bf16x8*)&sFb[lr][kt * 32 + kg * 8];
        bf16x8 a1 = *(const bf16x8*)&sFb[16 + lr][kt * 32 + kg * 8];
        bf16x8 b  = *(const bf16x8*)&bp1[kt * 32];
        acc0 = MFMA16(a0, b, acc0);
        acc1 = MFMA16(a1, b, acc1);
    }
    int col = wv * 16 + lr;
    float bj = b1eff[col], bw = bmW1[col];
#pragma unroll
    for (int rt = 0; rt < 2; rt++) {
        f32x4 acc = rt ? acc1 : acc0;
        int r0 = rt * 16 + kg * 4;
#pragma unroll
        for (int reg = 0; reg < 4; reg++) {
            float c = sCnt[r0 + reg];
            float hv = fmaxf(acc[reg] + (c > 0.f ? bj : bj - bw), 0.f);
            float other = __shfl_xor(hv, 1);
            if (!(lane & 1))
                ((uint32*)&sHb[r0 + reg][0])[col >> 1] = pack_bf16x2(hv, other);
        }
    }
    __syncthreads();

#pragma unroll
    for (int m = 0; m < 4; m++) {
        int d = c16 + 16 * m;
        if (vok) h1b[(size_t)v * 64 + d] = ((uint32*)&sHb[tr][0])[d];
    }

    int rt2 = wv >> 2, ct2 = wv & 3;
    f32x4 accg = {0.f, 0.f, 0.f, 0.f};
    const ushort16* bp2 = &Wm2hT[(size_t)(ct2 * 16 + lr) * 128 + kg * 8];
#pragma unroll
    for (int kt = 0; kt < 4; kt++) {
        bf16x8 a = *(const bf16x8*)&sHb[rt2 * 16 + lr][kt * 32 + kg * 8];
        bf16x8 b = *(const bf16x8*)&bp2[kt * 32];
        accg = MFMA16(a, b, accg);
    }
    int colg = ct2 * 16 + lr;
    int rg0 = rt2 * 16 + kg * 4;
#pragma unroll
    for (int reg = 0; reg < 4; reg++) {
        float other = __shfl_xor(accg[reg], 1);
        int vr = base + rg0 + reg;
        if (!(lane & 1) && vr < N)
            g2b[(size_t)vr * 32 + (colg >> 1)] = pack_bf16x2(accg[reg], other);
    }
}

// ---------------------------------------------------------------------------
// Layer-2 node kernel (MFMA) — unchanged from R8
// ---------------------------------------------------------------------------
__global__ __launch_bounds__(512) void node2_kernel(
    const uint32* __restrict__ h1b,    // [N][64] dwords
    const float* __restrict__ A2g,     // [N][64] f32
    const float* __restrict__ A1e,     // [N][32] f32
    const int*   __restrict__ deg,
    const ushort16* __restrict__ Wc2T, // [64][224] bf16
    const float* __restrict__ b2eff,
    const float* __restrict__ bmW2,
    float* __restrict__ out,
    int N)
{
    __shared__ ushort16 sFb[NPB][232];  // 224 used, 464B stride
    __shared__ float sCnt[NPB];

    int t = threadIdx.x;
    int base = blockIdx.x * NPB;
    int tr = t >> 4, c16 = t & 15;
    int v = base + tr;
    bool vok = v < N;

    uint32* sFrow = (uint32*)&sFb[tr][0];
#pragma unroll
    for (int m = 0; m < 7; m++) {
        int d = c16 + 16 * m;
        uint32 w = 0;
        if (vok) {
            if (d < 64) {
                w = h1b[(size_t)v * 64 + d];
            } else if (d < 96) {
                int o = (d - 64) * 2;
                w = pack_bf16x2(A2g[(size_t)v * 64 + o], A2g[(size_t)v * 64 + o + 1]);
            } else {
                int o = (d - 96) * 2;
                w = pack_bf16x2(A1e[(size_t)v * 32 + o], A1e[(size_t)v * 32 + o + 1]);
            }
        }
        sFrow[d] = w;
    }
    if (t < NPB) sCnt[t] = (base + t < N) ? (float)deg[base + t] : 1.f;
    __syncthreads();

    int lane = t & 63;
    int wv = t >> 6;
    int lr = lane & 15;
    int kg = lane >> 4;
    int rt = wv >> 2, ct = wv & 3;

    f32x4 acc = {0.f, 0.f, 0.f, 0.f};
    const ushort16* bp = &Wc2T[(size_t)(ct * 16 + lr) * 224 + kg * 8];
#pragma unroll
    for (int kt = 0; kt < 7; kt++) {
        bf16x8 a = *(const bf16x8*)&sFb[rt * 16 + lr][kt * 32 + kg * 8];
        bf16x8 b = *(const bf16x8*)&bp[kt * 32];
        acc = MFMA16(a, b, acc);
    }
    int col = ct * 16 + lr;
    float bj = b2eff[col], bw = bmW2[col];
    int r0 = rt * 16 + kg * 4;
#pragma unroll
    for (int reg = 0; reg < 4; reg++) {
        int vr = base + r0 + reg;
        float c = sCnt[r0 + reg];
        float bias = (c > 0.f) ? bj : bj - bw;
        if (vr < N) out[(size_t)vr * 64 + col] = fmaxf(acc[reg] + bias, 0.f);
    }
}

// ---------------------------------------------------------------------------
extern "C" void kernel_launch(void* const* d_in, const int* in_sizes, int n_in,
                              void* d_out, int out_size, void* d_ws, size_t ws_size,
                              hipStream_t stream) {
    const float* x      = (const float*)d_in[0];
    const int*   ei     = (const int*)d_in[1];
    const float* ea     = (const float*)d_in[2];
    const float* Wmsg1  = (const float*)d_in[3];
    const float* bmsg1  = (const float*)d_in[4];
    const float* Wapp1  = (const float*)d_in[5];
    const float* bapp1  = (const float*)d_in[6];
    const float* Wmsg2  = (const float*)d_in[7];
    const float* bmsg2  = (const float*)d_in[8];
    const float* Wapp2  = (const float*)d_in[9];
    const float* bapp2  = (const float*)d_in[10];

    const int N = in_sizes[0] / 64;      // 50000
    const int E = in_sizes[1] / 2;       // 800000
    const int NCH = (N + SCAN_CHUNK - 1) / SCAN_CHUNK;
    const int* src = ei;
    const int* dst = ei + E;

    uint8_t* p = (uint8_t*)d_ws;
    auto alloc = [&](size_t bytes) -> void* {
        void* r = (void*)p;
        p += (bytes + 255) & ~(size_t)255;
        return r;
    };
    int*     deg    = (int*)alloc((size_t)N * 4);
    int*     off    = (int*)alloc((size_t)(N + 1) * 4);
    int*     cursor = (int*)alloc((size_t)N * 4);
    int*     part   = (int*)alloc((size_t)NCH * 4);
    int2*    elist  = (int2*)alloc((size_t)E * 8);
    float*   A1x    = (float*)alloc((size_t)N * 64 * 4);  // reused as A2g
    float*   A1e    = (float*)alloc((size_t)N * 32 * 4);
    uint32*  xb     = (uint32*)alloc((size_t)N * 32 * 4);
    uint32*  h1b    = (uint32*)alloc((size_t)N * 64 * 4);
    uint32*  g2b    = (uint32*)alloc((size_t)N * 32 * 4);
    ushort16* Wc1T  = (ushort16*)alloc(128 * 160 * 2);
    ushort16* Wc2T  = (ushort16*)alloc(64 * 224 * 2);
    ushort16* Wm2hT = (ushort16*)alloc(64 * 128 * 2);
    float*   b1eff  = (float*)alloc(128 * 4);
    float*   bmW1   = (float*)alloc(128 * 4);
    float*   b2eff  = (float*)alloc(64 * 4);
    float*   bmW2   = (float*)alloc(64 * 4);
    float*   A2g    = A1x;   // safe: A1x consumed by node1 before agg2 writes A2g

    hipMemsetAsync(deg, 0, (size_t)N * 4, stream);

    // Weight composition + x conversion
    compose1_kernel<<<161, 128, 0, stream>>>(Wmsg1, bmsg1, Wapp1, bapp1,
                                             Wc1T, b1eff, bmW1);
    compose2_kernel<<<225, 64, 0, stream>>>(Wmsg2, bmsg2, Wapp2, bapp2,
                                            Wc2T, b2eff, bmW2);
    composem_kernel<<<128, 64, 0, stream>>>(Wmsg2, Wm2hT);
    {
        int n4 = N * 16;
        cvt_x_kernel<<<(n4 + 255) / 256, 256, 0, stream>>>(
            (const float4*)x, (uint2*)xb, n4);
    }

    // CSR build
    hist_kernel<<<(E + 255) / 256, 256, 0, stream>>>(dst, deg, E);
    scanA_kernel<<<NCH, 256, 0, stream>>>(deg, part, N);
    scanB_kernel<<<1, 64, 0, stream>>>(part, off + N, NCH);
    scanC_kernel<<<NCH, SCAN_CHUNK, 0, stream>>>(deg, part, off, cursor, N);
    fill_kernel<<<(E + 255) / 256, 256, 0, stream>>>(src, dst, cursor, elist, E);

    // Layer 1: 8 lanes/node -> 32 nodes per 256-thread block
    agg1_kernel<<<(N + 31) / 32, 256, 0, stream>>>(
        (const uint4*)xb, (const float4*)ea, elist, off,
        (float4*)A1x, (float4*)A1e, N);
    node1_kernel<<<(N + NPB - 1) / NPB, 512, 0, stream>>>(
        xb, A1x, A1e, deg, Wc1T, b1eff, bmW1, Wm2hT, h1b, g2b, N);

    // Layer 2
    agg2_kernel<<<(N + 31) / 32, 256, 0, stream>>>(
        (const uint4*)g2b, elist, off, (float4*)A2g, N);
    node2_kernel<<<(N + NPB - 1) / NPB, 512, 0, stream>>>(
        h1b, A2g, A1e, deg, Wc2T, b2eff, bmW2,
        (float*)d_out, N);
}

// Round 10
// 209.658 us; speedup vs baseline: 11.7029x; 1.0123x over previous
//
#include <hip/hip_runtime.h>

#define SCAN_CHUNK 1024
#define NPB 32

typedef unsigned int   uint32;
typedef unsigned short ushort16;
typedef __attribute__((ext_vector_type(8))) short bf16x8;
typedef __attribute__((ext_vector_type(4))) float f32x4;
#define MFMA16(a,b,c) __builtin_amdgcn_mfma_f32_16x16x32_bf16(a,b,c,0,0,0)

// bf16 helpers (RNE)
__device__ inline uint32 pack_bf16x2(float a, float b) {
    uint32 ua = __float_as_uint(a);
    uint32 ub = __float_as_uint(b);
    ua += 0x7FFFu + ((ua >> 16) & 1u);
    ub += 0x7FFFu + ((ub >> 16) & 1u);
    return (ua >> 16) | (ub & 0xFFFF0000u);
}
__device__ inline ushort16 bf16_1(float a) {
    uint32 u = __float_as_uint(a);
    u += 0x7FFFu + ((u >> 16) & 1u);
    return (ushort16)(u >> 16);
}
__device__ inline float bf_lo(uint32 u) { return __uint_as_float(u << 16); }
__device__ inline float bf_hi(uint32 u) { return __uint_as_float(u & 0xFFFF0000u); }

// ---------------------------------------------------------------------------
// x fp32 -> bf16
// ---------------------------------------------------------------------------
__global__ void cvt_x_kernel(const float4* __restrict__ xin,
                             uint2* __restrict__ xb, int n4)
{
    int i = blockIdx.x * blockDim.x + threadIdx.x;
    if (i < n4) {
        float4 v = xin[i];
        uint2 o;
        o.x = pack_bf16x2(v.x, v.y);
        o.y = pack_bf16x2(v.z, v.w);
        xb[i] = o;
    }
}

// ---------------------------------------------------------------------------
// CSR build
// ---------------------------------------------------------------------------
__global__ void hist_kernel(const int* __restrict__ dst, int* __restrict__ deg, int E)
{
    int e = blockIdx.x * blockDim.x + threadIdx.x;
    if (e < E) atomicAdd(&deg[dst[e]], 1);
}

__global__ __launch_bounds__(256) void scanA_kernel(const int* __restrict__ deg,
                                                    int* __restrict__ part, int N)
{
    __shared__ int red[256];
    int b = blockIdx.x, t = threadIdx.x;
    int base = b * SCAN_CHUNK;
    int s = 0;
    for (int i = t; i < SCAN_CHUNK; i += 256) {
        int idx = base + i;
        s += (idx < N) ? deg[idx] : 0;
    }
    red[t] = s;
    __syncthreads();
    for (int o = 128; o > 0; o >>= 1) {
        if (t < o) red[t] += red[t + o];
        __syncthreads();
    }
    if (t == 0) part[b] = red[0];
}

__global__ void scanB_kernel(int* __restrict__ part, int* __restrict__ offN, int NCH)
{
    int lane = threadIdx.x;
    int orig = (lane < NCH) ? part[lane] : 0;
    int v = orig;
    for (int s = 1; s < 64; s <<= 1) {
        int t = __shfl_up(v, s);
        if (lane >= s) v += t;
    }
    if (lane < NCH) part[lane] = v - orig;
    if (lane == NCH - 1) *offN = v;
}

__global__ __launch_bounds__(SCAN_CHUNK) void scanC_kernel(const int* __restrict__ deg,
                                                           const int* __restrict__ part,
                                                           int* __restrict__ off,
                                                           int* __restrict__ cursor, int N)
{
    __shared__ int buf[SCAN_CHUNK];
    int b = blockIdx.x, t = threadIdx.x;
    int idx = b * SCAN_CHUNK + t;
    int v = (idx < N) ? deg[idx] : 0;
    buf[t] = v;
    __syncthreads();
    for (int s = 1; s < SCAN_CHUNK; s <<= 1) {
        int tmp = (t >= s) ? buf[t - s] : 0;
        __syncthreads();
        buf[t] += tmp;
        __syncthreads();
    }
    int excl = buf[t] - v + part[b];
    if (idx < N) { off[idx] = excl; cursor[idx] = excl; }
}

__global__ void fill_kernel(const int* __restrict__ src, const int* __restrict__ dst,
                            int* __restrict__ cursor, int2* __restrict__ elist, int E)
{
    int e = blockIdx.x * blockDim.x + threadIdx.x;
    if (e >= E) return;
    int d = dst[e];
    int p = atomicAdd(&cursor[d], 1);
    elist[p] = make_int2(src[e], e);
}

// ---------------------------------------------------------------------------
// Weight composition (layer 1) -> transposed bf16 Wc1T[128][160]
// ---------------------------------------------------------------------------
__global__ __launch_bounds__(128) void compose1_kernel(
    const float* __restrict__ Wmsg1, const float* __restrict__ bmsg1,
    const float* __restrict__ Wapp1, const float* __restrict__ bapp1,
    ushort16* __restrict__ Wc1T, float* __restrict__ b1eff, float* __restrict__ bmW1)
{
    int b = blockIdx.x;   // k-row 0..160
    int j = threadIdx.x;  // 0..127
    if (b < 64) {
        Wc1T[(size_t)j * 160 + b] = bf16_1(Wapp1[b * 128 + j]);
    } else if (b < 160) {
        int ar = b - 64;
        float s = 0.f;
        for (int k = 0; k < 128; k++)
            s = fmaf(Wmsg1[ar * 128 + k], Wapp1[(64 + k) * 128 + j], s);
        Wc1T[(size_t)j * 160 + b] = bf16_1(s);
    } else {
        float s = 0.f;
        for (int k = 0; k < 128; k++)
            s = fmaf(bmsg1[k], Wapp1[(64 + k) * 128 + j], s);
        bmW1[j] = s;
        b1eff[j] = bapp1[j] + s;
    }
}

// ---------------------------------------------------------------------------
// Weight composition (layer 2) -> transposed bf16 Wc2T[64][224]
// ---------------------------------------------------------------------------
__global__ __launch_bounds__(64) void compose2_kernel(
    const float* __restrict__ Wmsg2, const float* __restrict__ bmsg2,
    const float* __restrict__ Wapp2, const float* __restrict__ bapp2,
    ushort16* __restrict__ Wc2T, float* __restrict__ b2eff, float* __restrict__ bmW2)
{
    int b = blockIdx.x;  // 0..224
    int j = threadIdx.x; // 0..63
    if (b < 192) {
        Wc2T[(size_t)j * 224 + b] = bf16_1(Wapp2[b * 64 + j]);
    } else if (b < 224) {
        int ar = 128 + (b - 192);
        float s = 0.f;
        for (int k = 0; k < 64; k++)
            s = fmaf(Wmsg2[ar * 64 + k], Wapp2[(128 + k) * 64 + j], s);
        Wc2T[(size_t)j * 224 + b] = bf16_1(s);
    } else {
        float s = 0.f;
        for (int k = 0; k < 64; k++)
            s = fmaf(bmsg2[k], Wapp2[(128 + k) * 64 + j], s);
        bmW2[j] = s;
        b2eff[j] = bapp2[j] + s;
    }
}

// Wm2hT[64][128] bf16 = transpose of Wmsg2 rows 0..127
__global__ __launch_bounds__(64) void composem_kernel(
    const float* __restrict__ Wmsg2, ushort16* __restrict__ Wm2hT)
{
    int k = blockIdx.x;   // 0..127
    int c = threadIdx.x;  // 0..63
    Wm2hT[(size_t)c * 128 + k] = bf16_1(Wmsg2[k * 64 + c]);
}

// ---------------------------------------------------------------------------
// Layer-1 aggregate: 8 nodes/wave, 8-lane group per node, 4-way unrolled
// gather batches (8 VMEM in flight per lane) to break the latency chain.
// ---------------------------------------------------------------------------
__global__ __launch_bounds__(256) void agg1_kernel(const uint4* __restrict__ xb,
                                                   const float4* __restrict__ ea4,
                                                   const int2* __restrict__ elist,
                                                   const int* __restrict__ off,
                                                   float4* __restrict__ A1x,
                                                   float4* __restrict__ A1e, int N)
{
    int tid = blockIdx.x * blockDim.x + threadIdx.x;
    int node = tid >> 3;          // 8 lanes per node
    int s8 = tid & 7;
    if (node >= N) return;
    int beg = off[node], end = off[node + 1];
    float inv = 1.0f / fmaxf((float)(end - beg), 1.0f);

    float ax[8];
#pragma unroll
    for (int q = 0; q < 8; q++) ax[q] = 0.f;
    float4 ae = make_float4(0.f, 0.f, 0.f, 0.f);

    int i = beg;
    for (; i + 4 <= end; i += 4) {
        int2 p0 = elist[i + 0];
        int2 p1 = elist[i + 1];
        int2 p2 = elist[i + 2];
        int2 p3 = elist[i + 3];
        uint4 vx0 = xb[(size_t)p0.x * 8 + s8];
        uint4 vx1 = xb[(size_t)p1.x * 8 + s8];
        uint4 vx2 = xb[(size_t)p2.x * 8 + s8];
        uint4 vx3 = xb[(size_t)p3.x * 8 + s8];
        float4 ve0 = ea4[(size_t)p0.y * 8 + s8];
        float4 ve1 = ea4[(size_t)p1.y * 8 + s8];
        float4 ve2 = ea4[(size_t)p2.y * 8 + s8];
        float4 ve3 = ea4[(size_t)p3.y * 8 + s8];
        ax[0] += (bf_lo(vx0.x) + bf_lo(vx1.x)) + (bf_lo(vx2.x) + bf_lo(vx3.x));
        ax[1] += (bf_hi(vx0.x) + bf_hi(vx1.x)) + (bf_hi(vx2.x) + bf_hi(vx3.x));
        ax[2] += (bf_lo(vx0.y) + bf_lo(vx1.y)) + (bf_lo(vx2.y) + bf_lo(vx3.y));
        ax[3] += (bf_hi(vx0.y) + bf_hi(vx1.y)) + (bf_hi(vx2.y) + bf_hi(vx3.y));
        ax[4] += (bf_lo(vx0.z) + bf_lo(vx1.z)) + (bf_lo(vx2.z) + bf_lo(vx3.z));
        ax[5] += (bf_hi(vx0.z) + bf_hi(vx1.z)) + (bf_hi(vx2.z) + bf_hi(vx3.z));
        ax[6] += (bf_lo(vx0.w) + bf_lo(vx1.w)) + (bf_lo(vx2.w) + bf_lo(vx3.w));
        ax[7] += (bf_hi(vx0.w) + bf_hi(vx1.w)) + (bf_hi(vx2.w) + bf_hi(vx3.w));
        ae.x += (ve0.x + ve1.x) + (ve2.x + ve3.x);
        ae.y += (ve0.y + ve1.y) + (ve2.y + ve3.y);
        ae.z += (ve0.z + ve1.z) + (ve2.z + ve3.z);
        ae.w += (ve0.w + ve1.w) + (ve2.w + ve3.w);
    }
    for (; i < end; i++) {
        int2 pr = elist[i];
        uint4 vx = xb[(size_t)pr.x * 8 + s8];
        float4 ve = ea4[(size_t)pr.y * 8 + s8];
        ax[0] += bf_lo(vx.x); ax[1] += bf_hi(vx.x);
        ax[2] += bf_lo(vx.y); ax[3] += bf_hi(vx.y);
        ax[4] += bf_lo(vx.z); ax[5] += bf_hi(vx.z);
        ax[6] += bf_lo(vx.w); ax[7] += bf_hi(vx.w);
        ae.x += ve.x; ae.y += ve.y; ae.z += ve.z; ae.w += ve.w;
    }
    float4 o0 = make_float4(ax[0] * inv, ax[1] * inv, ax[2] * inv, ax[3] * inv);
    float4 o1 = make_float4(ax[4] * inv, ax[5] * inv, ax[6] * inv, ax[7] * inv);
    A1x[(size_t)node * 16 + s8 * 2 + 0] = o0;
    A1x[(size_t)node * 16 + s8 * 2 + 1] = o1;
    ae.x *= inv; ae.y *= inv; ae.z *= inv; ae.w *= inv;
    A1e[(size_t)node * 8 + s8] = ae;
}

// ---------------------------------------------------------------------------
// Layer-2 aggregate: same structure, 4-way unrolled.
// ---------------------------------------------------------------------------
__global__ __launch_bounds__(256) void agg2_kernel(const uint4* __restrict__ g2b,
                                                   const int2* __restrict__ elist,
                                                   const int* __restrict__ off,
                                                   float4* __restrict__ A2g, int N)
{
    int tid = blockIdx.x * blockDim.x + threadIdx.x;
    int node = tid >> 3;
    int s8 = tid & 7;
    if (node >= N) return;
    int beg = off[node], end = off[node + 1];
    float inv = 1.0f / fmaxf((float)(end - beg), 1.0f);

    float ag[8];
#pragma unroll
    for (int q = 0; q < 8; q++) ag[q] = 0.f;

    int i = beg;
    for (; i + 4 <= end; i += 4) {
        int r0 = elist[i + 0].x;
        int r1 = elist[i + 1].x;
        int r2 = elist[i + 2].x;
        int r3 = elist[i + 3].x;
        uint4 v0 = g2b[(size_t)r0 * 8 + s8];
        uint4 v1 = g2b[(size_t)r1 * 8 + s8];
        uint4 v2 = g2b[(size_t)r2 * 8 + s8];
        uint4 v3 = g2b[(size_t)r3 * 8 + s8];
        ag[0] += (bf_lo(v0.x) + bf_lo(v1.x)) + (bf_lo(v2.x) + bf_lo(v3.x));
        ag[1] += (bf_hi(v0.x) + bf_hi(v1.x)) + (bf_hi(v2.x) + bf_hi(v3.x));
        ag[2] += (bf_lo(v0.y) + bf_lo(v1.y)) + (bf_lo(v2.y) + bf_lo(v3.y));
        ag[3] += (bf_hi(v0.y) + bf_hi(v1.y)) + (bf_hi(v2.y) + bf_hi(v3.y));
        ag[4] += (bf_lo(v0.z) + bf_lo(v1.z)) + (bf_lo(v2.z) + bf_lo(v3.z));
        ag[5] += (bf_hi(v0.z) + bf_hi(v1.z)) + (bf_hi(v2.z) + bf_hi(v3.z));
        ag[6] += (bf_lo(v0.w) + bf_lo(v1.w)) + (bf_lo(v2.w) + bf_lo(v3.w));
        ag[7] += (bf_hi(v0.w) + bf_hi(v1.w)) + (bf_hi(v2.w) + bf_hi(v3.w));
    }
    for (; i < end; i++) {
        int row = elist[i].x;
        uint4 v = g2b[(size_t)row * 8 + s8];
        ag[0] += bf_lo(v.x); ag[1] += bf_hi(v.x);
        ag[2] += bf_lo(v.y); ag[3] += bf_hi(v.y);
        ag[4] += bf_lo(v.z); ag[5] += bf_hi(v.z);
        ag[6] += bf_lo(v.w); ag[7] += bf_hi(v.w);
    }
    float4 o0 = make_float4(ag[0] * inv, ag[1] * inv, ag[2] * inv, ag[3] * inv);
    float4 o1 = make_float4(ag[4] * inv, ag[5] * inv, ag[6] * inv, ag[7] * inv);
    A2g[(size_t)node * 16 + s8 * 2 + 0] = o0;
    A2g[(size_t)node * 16 + s8 * 2 + 1] = o1;
}

// ---------------------------------------------------------------------------
// Layer-1 node kernel (MFMA) — unchanged from R8
// ---------------------------------------------------------------------------
__global__ __launch_bounds__(512) void node1_kernel(
    const uint32* __restrict__ xb,     // [N][32] dwords (bf16x2)
    const float* __restrict__ A1x,     // [N][64] f32
    const float* __restrict__ A1e,     // [N][32] f32
    const int*   __restrict__ deg,
    const ushort16* __restrict__ Wc1T, // [128][160] bf16
    const float* __restrict__ b1eff,
    const float* __restrict__ bmW1,
    const ushort16* __restrict__ Wm2hT,// [64][128] bf16
    uint32* __restrict__ h1b,          // [N][64] dwords (bf16x2)
    uint32* __restrict__ g2b,          // [N][32] dwords (bf16x2)
    int N)
{
    __shared__ ushort16 sFb[NPB][168];  // 160 used, 336B stride
    __shared__ ushort16 sHb[NPB][168];  // 128 used
    __shared__ float sCnt[NPB];

    int t = threadIdx.x;
    int base = blockIdx.x * NPB;
    int tr = t >> 4, c16 = t & 15;
    int v = base + tr;
    bool vok = v < N;

    uint32* sFrow = (uint32*)&sFb[tr][0];
#pragma unroll
    for (int m = 0; m < 5; m++) {
        int d = c16 + 16 * m;
        uint32 w = 0;
        if (vok) {
            if (d < 32) {
                w = xb[(size_t)v * 32 + d];
            } else if (d < 64) {
                int o = (d - 32) * 2;
                w = pack_bf16x2(A1x[(size_t)v * 64 + o], A1x[(size_t)v * 64 + o + 1]);
            } else {
                int o = (d - 64) * 2;
                w = pack_bf16x2(A1e[(size_t)v * 32 + o], A1e[(size_t)v * 32 + o + 1]);
            }
        }
        sFrow[d] = w;
    }
    if (t < NPB) sCnt[t] = (base + t < N) ? (float)deg[base + t] : 1.f;
    __syncthreads();

    int lane = t & 63;
    int wv = t >> 6;
    int lr = lane & 15;
    int kg = lane >> 4;

    f32x4 acc0 = {0.f, 0.f, 0.f, 0.f};
    f32x4 acc1 = {0.f, 0.f, 0.f, 0.f};
    const ushort16* bp1 = &Wc1T[(size_t)(wv * 16 + lr) * 160 + kg * 8];
#pragma unroll
    for (int kt = 0; kt < 5; kt++) {
        bf16x8 a0 = *(const bf16x8*)&sFb[lr][kt * 32 + kg * 8];
        bf16x8 a1 = *(const bf16x8*)&sFb[16 + lr][kt * 32 + kg * 8];
        bf16x8 b  = *(const bf16x8*)&bp1[kt * 32];
        acc0 = MFMA16(a0, b, acc0);
        acc1 = MFMA16(a1, b, acc1);
    }
    int col = wv * 16 + lr;
    float bj = b1eff[col], bw = bmW1[col];
#pragma unroll
    for (int rt = 0; rt < 2; rt++) {
        f32x4 acc = rt ? acc1 : acc0;
        int r0 = rt * 16 + kg * 4;
#pragma unroll
        for (int reg = 0; reg < 4; reg++) {
            float c = sCnt[r0 + reg];
            float hv = fmaxf(acc[reg] + (c > 0.f ? bj : bj - bw), 0.f);
            float other = __shfl_xor(hv, 1);
            if (!(lane & 1))
                ((uint32*)&sHb[r0 + reg][0])[col >> 1] = pack_bf16x2(hv, other);
        }
    }
    __syncthreads();

#pragma unroll
    for (int m = 0; m < 4; m++) {
        int d = c16 + 16 * m;
        if (vok) h1b[(size_t)v * 64 + d] = ((uint32*)&sHb[tr][0])[d];
    }

    int rt2 = wv >> 2, ct2 = wv & 3;
    f32x4 accg = {0.f, 0.f, 0.f, 0.f};
    const ushort16* bp2 = &Wm2hT[(size_t)(ct2 * 16 + lr) * 128 + kg * 8];
#pragma unroll
    for (int kt = 0; kt < 4; kt++) {
        bf16x8 a = *(const bf16x8*)&sHb[rt2 * 16 + lr][kt * 32 + kg * 8];
        bf16x8 b = *(const bf16x8*)&bp2[kt * 32];
        accg = MFMA16(a, b, accg);
    }
    int colg = ct2 * 16 + lr;
    int rg0 = rt2 * 16 + kg * 4;
#pragma unroll
    for (int reg = 0; reg < 4; reg++) {
        float other = __shfl_xor(accg[reg], 1);
        int vr = base + rg0 + reg;
        if (!(lane & 1) && vr < N)
            g2b[(size_t)vr * 32 + (colg >> 1)] = pack_bf16x2(accg[reg], other);
    }
}

// ---------------------------------------------------------------------------
// Layer-2 node kernel (MFMA) — unchanged from R8
// ---------------------------------------------------------------------------
__global__ __launch_bounds__(512) void node2_kernel(
    const uint32* __restrict__ h1b,    // [N][64] dwords
    const float* __restrict__ A2g,     // [N][64] f32
    const float* __restrict__ A1e,     // [N][32] f32
    const int*   __restrict__ deg,
    const ushort16* __restrict__ Wc2T, // [64][224] bf16
    const float* __restrict__ b2eff,
    const float* __restrict__ bmW2,
    float* __restrict__ out,
    int N)
{
    __shared__ ushort16 sFb[NPB][232];  // 224 used, 464B stride
    __shared__ float sCnt[NPB];

    int t = threadIdx.x;
    int base = blockIdx.x * NPB;
    int tr = t >> 4, c16 = t & 15;
    int v = base + tr;
    bool vok = v < N;

    uint32* sFrow = (uint32*)&sFb[tr][0];
#pragma unroll
    for (int m = 0; m < 7; m++) {
        int d = c16 + 16 * m;
        uint32 w = 0;
        if (vok) {
            if (d < 64) {
                w = h1b[(size_t)v * 64 + d];
            } else if (d < 96) {
                int o = (d - 64) * 2;
                w = pack_bf16x2(A2g[(size_t)v * 64 + o], A2g[(size_t)v * 64 + o + 1]);
            } else {
                int o = (d - 96) * 2;
                w = pack_bf16x2(A1e[(size_t)v * 32 + o], A1e[(size_t)v * 32 + o + 1]);
            }
        }
        sFrow[d] = w;
    }
    if (t < NPB) sCnt[t] = (base + t < N) ? (float)deg[base + t] : 1.f;
    __syncthreads();

    int lane = t & 63;
    int wv = t >> 6;
    int lr = lane & 15;
    int kg = lane >> 4;
    int rt = wv >> 2, ct = wv & 3;

    f32x4 acc = {0.f, 0.f, 0.f, 0.f};
    const ushort16* bp = &Wc2T[(size_t)(ct * 16 + lr) * 224 + kg * 8];
#pragma unroll
    for (int kt = 0; kt < 7; kt++) {
        bf16x8 a = *(const bf16x8*)&sFb[rt * 16 + lr][kt * 32 + kg * 8];
        bf16x8 b = *(const bf16x8*)&bp[kt * 32];
        acc = MFMA16(a, b, acc);
    }
    int col = ct * 16 + lr;
    float bj = b2eff[col], bw = bmW2[col];
    int r0 = rt * 16 + kg * 4;
#pragma unroll
    for (int reg = 0; reg < 4; reg++) {
        int vr = base + r0 + reg;
        float c = sCnt[r0 + reg];
        float bias = (c > 0.f) ? bj : bj - bw;
        if (vr < N) out[(size_t)vr * 64 + col] = fmaxf(acc[reg] + bias, 0.f);
    }
}

// ---------------------------------------------------------------------------
extern "C" void kernel_launch(void* const* d_in, const int* in_sizes, int n_in,
                              void* d_out, int out_size, void* d_ws, size_t ws_size,
                              hipStream_t stream) {
    const float* x      = (const float*)d_in[0];
    const int*   ei     = (const int*)d_in[1];
    const float* ea     = (const float*)d_in[2];
    const float* Wmsg1  = (const float*)d_in[3];
    const float* bmsg1  = (const float*)d_in[4];
    const float* Wapp1  = (const float*)d_in[5];
    const float* bapp1  = (const float*)d_in[6];
    const float* Wmsg2  = (const float*)d_in[7];
    const float* bmsg2  = (const float*)d_in[8];
    const float* Wapp2  = (const float*)d_in[9];
    const float* bapp2  = (const float*)d_in[10];

    const int N = in_sizes[0] / 64;      // 50000
    const int E = in_sizes[1] / 2;       // 800000
    const int NCH = (N + SCAN_CHUNK - 1) / SCAN_CHUNK;
    const int* src = ei;
    const int* dst = ei + E;

    uint8_t* p = (uint8_t*)d_ws;
    auto alloc = [&](size_t bytes) -> void* {
        void* r = (void*)p;
        p += (bytes + 255) & ~(size_t)255;
        return r;
    };
    int*     deg    = (int*)alloc((size_t)N * 4);
    int*     off    = (int*)alloc((size_t)(N + 1) * 4);
    int*     cursor = (int*)alloc((size_t)N * 4);
    int*     part   = (int*)alloc((size_t)NCH * 4);
    int2*    elist  = (int2*)alloc((size_t)E * 8);
    float*   A1x    = (float*)alloc((size_t)N * 64 * 4);  // reused as A2g
    float*   A1e    = (float*)alloc((size_t)N * 32 * 4);
    uint32*  xb     = (uint32*)alloc((size_t)N * 32 * 4);
    uint32*  h1b    = (uint32*)alloc((size_t)N * 64 * 4);
    uint32*  g2b    = (uint32*)alloc((size_t)N * 32 * 4);
    ushort16* Wc1T  = (ushort16*)alloc(128 * 160 * 2);
    ushort16* Wc2T  = (ushort16*)alloc(64 * 224 * 2);
    ushort16* Wm2hT = (ushort16*)alloc(64 * 128 * 2);
    float*   b1eff  = (float*)alloc(128 * 4);
    float*   bmW1   = (float*)alloc(128 * 4);
    float*   b2eff  = (float*)alloc(64 * 4);
    float*   bmW2   = (float*)alloc(64 * 4);
    float*   A2g    = A1x;   // safe: A1x consumed by node1 before agg2 writes A2g

    hipMemsetAsync(deg, 0, (size_t)N * 4, stream);

    // Weight composition + x conversion
    compose1_kernel<<<161, 128, 0, stream>>>(Wmsg1, bmsg1, Wapp1, bapp1,
                                             Wc1T, b1eff, bmW1);
    compose2_kernel<<<225, 64, 0, stream>>>(Wmsg2, bmsg2, Wapp2, bapp2,
                                            Wc2T, b2eff, bmW2);
    composem_kernel<<<128, 64, 0, stream>>>(Wmsg2, Wm2hT);
    {
        int n4 = N * 16;
        cvt_x_kernel<<<(n4 + 255) / 256, 256, 0, stream>>>(
            (const float4*)x, (uint2*)xb, n4);
    }

    // CSR build
    hist_kernel<<<(E + 255) / 256, 256, 0, stream>>>(dst, deg, E);
    scanA_kernel<<<NCH, 256, 0, stream>>>(deg, part, N);
    scanB_kernel<<<1, 64, 0, stream>>>(part, off + N, NCH);
    scanC_kernel<<<NCH, SCAN_CHUNK, 0, stream>>>(deg, part, off, cursor, N);
    fill_kernel<<<(E + 255) / 256, 256, 0, stream>>>(src, dst, cursor, elist, E);

    // Layer 1: 8 lanes/node -> 32 nodes per 256-thread block
    agg1_kernel<<<(N + 31) / 32, 256, 0, stream>>>(
        (const uint4*)xb, (const float4*)ea, elist, off,
        (float4*)A1x, (float4*)A1e, N);
    node1_kernel<<<(N + NPB - 1) / NPB, 512, 0, stream>>>(
        xb, A1x, A1e, deg, Wc1T, b1eff, bmW1, Wm2hT, h1b, g2b, N);

    // Layer 2
    agg2_kernel<<<(N + 31) / 32, 256, 0, stream>>>(
        (const uint4*)g2b, elist, off, (float4*)A2g, N);
    node2_kernel<<<(N + NPB - 1) / NPB, 512, 0, stream>>>(
        h1b, A2g, A1e, deg, Wc2T, b2eff, bmW2,
        (float*)d_out, N);
}

// Round 11
// 196.787 us; speedup vs baseline: 12.4684x; 1.0654x over previous
//
#include <hip/hip_runtime.h>

#define SCAN_CHUNK 1024
#define NPB 32

typedef unsigned int   uint32;
typedef unsigned short ushort16;
typedef __attribute__((ext_vector_type(8))) short bf16x8;
typedef __attribute__((ext_vector_type(4))) float f32x4;
#define MFMA16(a,b,c) __builtin_amdgcn_mfma_f32_16x16x32_bf16(a,b,c,0,0,0)

// bf16 helpers (RNE)
__device__ inline uint32 pack_bf16x2(float a, float b) {
    uint32 ua = __float_as_uint(a);
    uint32 ub = __float_as_uint(b);
    ua += 0x7FFFu + ((ua >> 16) & 1u);
    ub += 0x7FFFu + ((ub >> 16) & 1u);
    return (ua >> 16) | (ub & 0xFFFF0000u);
}
__device__ inline ushort16 bf16_1(float a) {
    uint32 u = __float_as_uint(a);
    u += 0x7FFFu + ((u >> 16) & 1u);
    return (ushort16)(u >> 16);
}
__device__ inline float bf_lo(uint32 u) { return __uint_as_float(u << 16); }
__device__ inline float bf_hi(uint32 u) { return __uint_as_float(u & 0xFFFF0000u); }

// ---------------------------------------------------------------------------
// x fp32 -> bf16
// ---------------------------------------------------------------------------
__global__ void cvt_x_kernel(const float4* __restrict__ xin,
                             uint2* __restrict__ xb, int n4)
{
    int i = blockIdx.x * blockDim.x + threadIdx.x;
    if (i < n4) {
        float4 v = xin[i];
        uint2 o;
        o.x = pack_bf16x2(v.x, v.y);
        o.y = pack_bf16x2(v.z, v.w);
        xb[i] = o;
    }
}

// ---------------------------------------------------------------------------
// CSR build: 8 edges/thread for memory-level parallelism
// ---------------------------------------------------------------------------
__global__ void hist_kernel(const int* __restrict__ dst, int* __restrict__ deg, int E)
{
    int g = blockIdx.x * blockDim.x + threadIdx.x;
    int e0 = g * 8;
    if (e0 + 8 <= E) {
        int4 da = *(const int4*)&dst[e0];
        int4 db = *(const int4*)&dst[e0 + 4];
        atomicAdd(&deg[da.x], 1);
        atomicAdd(&deg[da.y], 1);
        atomicAdd(&deg[da.z], 1);
        atomicAdd(&deg[da.w], 1);
        atomicAdd(&deg[db.x], 1);
        atomicAdd(&deg[db.y], 1);
        atomicAdd(&deg[db.z], 1);
        atomicAdd(&deg[db.w], 1);
    } else {
        for (int e = e0; e < E; e++) atomicAdd(&deg[dst[e]], 1);
    }
}

__global__ __launch_bounds__(256) void scanA_kernel(const int* __restrict__ deg,
                                                    int* __restrict__ part, int N)
{
    __shared__ int red[256];
    int b = blockIdx.x, t = threadIdx.x;
    int base = b * SCAN_CHUNK;
    int s = 0;
    for (int i = t; i < SCAN_CHUNK; i += 256) {
        int idx = base + i;
        s += (idx < N) ? deg[idx] : 0;
    }
    red[t] = s;
    __syncthreads();
    for (int o = 128; o > 0; o >>= 1) {
        if (t < o) red[t] += red[t + o];
        __syncthreads();
    }
    if (t == 0) part[b] = red[0];
}

__global__ void scanB_kernel(int* __restrict__ part, int* __restrict__ offN, int NCH)
{
    int lane = threadIdx.x;
    int orig = (lane < NCH) ? part[lane] : 0;
    int v = orig;
    for (int s = 1; s < 64; s <<= 1) {
        int t = __shfl_up(v, s);
        if (lane >= s) v += t;
    }
    if (lane < NCH) part[lane] = v - orig;
    if (lane == NCH - 1) *offN = v;
}

__global__ __launch_bounds__(SCAN_CHUNK) void scanC_kernel(const int* __restrict__ deg,
                                                           const int* __restrict__ part,
                                                           int* __restrict__ off,
                                                           int* __restrict__ cursor, int N)
{
    __shared__ int buf[SCAN_CHUNK];
    int b = blockIdx.x, t = threadIdx.x;
    int idx = b * SCAN_CHUNK + t;
    int v = (idx < N) ? deg[idx] : 0;
    buf[t] = v;
    __syncthreads();
    for (int s = 1; s < SCAN_CHUNK; s <<= 1) {
        int tmp = (t >= s) ? buf[t - s] : 0;
        __syncthreads();
        buf[t] += tmp;
        __syncthreads();
    }
    int excl = buf[t] - v + part[b];
    if (idx < N) { off[idx] = excl; cursor[idx] = excl; }
}

// 8 edges/thread: 2x int4 coalesced loads, 8 independent atomics, 8 stores
__global__ void fill_kernel(const int* __restrict__ src, const int* __restrict__ dst,
                            int* __restrict__ cursor, int2* __restrict__ elist, int E)
{
    int g = blockIdx.x * blockDim.x + threadIdx.x;
    int e0 = g * 8;
    if (e0 + 8 <= E) {
        int4 sa = *(const int4*)&src[e0];
        int4 sb = *(const int4*)&src[e0 + 4];
        int4 da = *(const int4*)&dst[e0];
        int4 db = *(const int4*)&dst[e0 + 4];
        int p0 = atomicAdd(&cursor[da.x], 1);
        int p1 = atomicAdd(&cursor[da.y], 1);
        int p2 = atomicAdd(&cursor[da.z], 1);
        int p3 = atomicAdd(&cursor[da.w], 1);
        int p4 = atomicAdd(&cursor[db.x], 1);
        int p5 = atomicAdd(&cursor[db.y], 1);
        int p6 = atomicAdd(&cursor[db.z], 1);
        int p7 = atomicAdd(&cursor[db.w], 1);
        elist[p0] = make_int2(sa.x, e0 + 0);
        elist[p1] = make_int2(sa.y, e0 + 1);
        elist[p2] = make_int2(sa.z, e0 + 2);
        elist[p3] = make_int2(sa.w, e0 + 3);
        elist[p4] = make_int2(sb.x, e0 + 4);
        elist[p5] = make_int2(sb.y, e0 + 5);
        elist[p6] = make_int2(sb.z, e0 + 6);
        elist[p7] = make_int2(sb.w, e0 + 7);
    } else {
        for (int e = e0; e < E; e++) {
            int p = atomicAdd(&cursor[dst[e]], 1);
            elist[p] = make_int2(src[e], e);
        }
    }
}

// ---------------------------------------------------------------------------
// Weight composition (layer 1) -> transposed bf16 Wc1T[128][160]
// ---------------------------------------------------------------------------
__global__ __launch_bounds__(128) void compose1_kernel(
    const float* __restrict__ Wmsg1, const float* __restrict__ bmsg1,
    const float* __restrict__ Wapp1, const float* __restrict__ bapp1,
    ushort16* __restrict__ Wc1T, float* __restrict__ b1eff, float* __restrict__ bmW1)
{
    int b = blockIdx.x;   // k-row 0..160
    int j = threadIdx.x;  // 0..127
    if (b < 64) {
        Wc1T[(size_t)j * 160 + b] = bf16_1(Wapp1[b * 128 + j]);
    } else if (b < 160) {
        int ar = b - 64;
        float s = 0.f;
        for (int k = 0; k < 128; k++)
            s = fmaf(Wmsg1[ar * 128 + k], Wapp1[(64 + k) * 128 + j], s);
        Wc1T[(size_t)j * 160 + b] = bf16_1(s);
    } else {
        float s = 0.f;
        for (int k = 0; k < 128; k++)
            s = fmaf(bmsg1[k], Wapp1[(64 + k) * 128 + j], s);
        bmW1[j] = s;
        b1eff[j] = bapp1[j] + s;
    }
}

// ---------------------------------------------------------------------------
// Weight composition (layer 2) -> transposed bf16 Wc2T[64][224]
// ---------------------------------------------------------------------------
__global__ __launch_bounds__(64) void compose2_kernel(
    const float* __restrict__ Wmsg2, const float* __restrict__ bmsg2,
    const float* __restrict__ Wapp2, const float* __restrict__ bapp2,
    ushort16* __restrict__ Wc2T, float* __restrict__ b2eff, float* __restrict__ bmW2)
{
    int b = blockIdx.x;  // 0..224
    int j = threadIdx.x; // 0..63
    if (b < 192) {
        Wc2T[(size_t)j * 224 + b] = bf16_1(Wapp2[b * 64 + j]);
    } else if (b < 224) {
        int ar = 128 + (b - 192);
        float s = 0.f;
        for (int k = 0; k < 64; k++)
            s = fmaf(Wmsg2[ar * 64 + k], Wapp2[(128 + k) * 64 + j], s);
        Wc2T[(size_t)j * 224 + b] = bf16_1(s);
    } else {
        float s = 0.f;
        for (int k = 0; k < 64; k++)
            s = fmaf(bmsg2[k], Wapp2[(128 + k) * 64 + j], s);
        bmW2[j] = s;
        b2eff[j] = bapp2[j] + s;
    }
}

// Wm2hT[64][128] bf16 = transpose of Wmsg2 rows 0..127
__global__ __launch_bounds__(64) void composem_kernel(
    const float* __restrict__ Wmsg2, ushort16* __restrict__ Wm2hT)
{
    int k = blockIdx.x;   // 0..127
    int c = threadIdx.x;  // 0..63
    Wm2hT[(size_t)c * 128 + k] = bf16_1(Wmsg2[k * 64 + c]);
}

// ---------------------------------------------------------------------------
// Layer-1 aggregate: 8 nodes/wave, 8-lane group per node, 4-way unrolled
// ---------------------------------------------------------------------------
__global__ __launch_bounds__(256) void agg1_kernel(const uint4* __restrict__ xb,
                                                   const float4* __restrict__ ea4,
                                                   const int2* __restrict__ elist,
                                                   const int* __restrict__ off,
                                                   float4* __restrict__ A1x,
                                                   float4* __restrict__ A1e, int N)
{
    int tid = blockIdx.x * blockDim.x + threadIdx.x;
    int node = tid >> 3;          // 8 lanes per node
    int s8 = tid & 7;
    if (node >= N) return;
    int beg = off[node], end = off[node + 1];
    float inv = 1.0f / fmaxf((float)(end - beg), 1.0f);

    float ax[8];
#pragma unroll
    for (int q = 0; q < 8; q++) ax[q] = 0.f;
    float4 ae = make_float4(0.f, 0.f, 0.f, 0.f);

    int i = beg;
    for (; i + 4 <= end; i += 4) {
        int2 p0 = elist[i + 0];
        int2 p1 = elist[i + 1];
        int2 p2 = elist[i + 2];
        int2 p3 = elist[i + 3];
        uint4 vx0 = xb[(size_t)p0.x * 8 + s8];
        uint4 vx1 = xb[(size_t)p1.x * 8 + s8];
        uint4 vx2 = xb[(size_t)p2.x * 8 + s8];
        uint4 vx3 = xb[(size_t)p3.x * 8 + s8];
        float4 ve0 = ea4[(size_t)p0.y * 8 + s8];
        float4 ve1 = ea4[(size_t)p1.y * 8 + s8];
        float4 ve2 = ea4[(size_t)p2.y * 8 + s8];
        float4 ve3 = ea4[(size_t)p3.y * 8 + s8];
        ax[0] += (bf_lo(vx0.x) + bf_lo(vx1.x)) + (bf_lo(vx2.x) + bf_lo(vx3.x));
        ax[1] += (bf_hi(vx0.x) + bf_hi(vx1.x)) + (bf_hi(vx2.x) + bf_hi(vx3.x));
        ax[2] += (bf_lo(vx0.y) + bf_lo(vx1.y)) + (bf_lo(vx2.y) + bf_lo(vx3.y));
        ax[3] += (bf_hi(vx0.y) + bf_hi(vx1.y)) + (bf_hi(vx2.y) + bf_hi(vx3.y));
        ax[4] += (bf_lo(vx0.z) + bf_lo(vx1.z)) + (bf_lo(vx2.z) + bf_lo(vx3.z));
        ax[5] += (bf_hi(vx0.z) + bf_hi(vx1.z)) + (bf_hi(vx2.z) + bf_hi(vx3.z));
        ax[6] += (bf_lo(vx0.w) + bf_lo(vx1.w)) + (bf_lo(vx2.w) + bf_lo(vx3.w));
        ax[7] += (bf_hi(vx0.w) + bf_hi(vx1.w)) + (bf_hi(vx2.w) + bf_hi(vx3.w));
        ae.x += (ve0.x + ve1.x) + (ve2.x + ve3.x);
        ae.y += (ve0.y + ve1.y) + (ve2.y + ve3.y);
        ae.z += (ve0.z + ve1.z) + (ve2.z + ve3.z);
        ae.w += (ve0.w + ve1.w) + (ve2.w + ve3.w);
    }
    for (; i < end; i++) {
        int2 pr = elist[i];
        uint4 vx = xb[(size_t)pr.x * 8 + s8];
        float4 ve = ea4[(size_t)pr.y * 8 + s8];
        ax[0] += bf_lo(vx.x); ax[1] += bf_hi(vx.x);
        ax[2] += bf_lo(vx.y); ax[3] += bf_hi(vx.y);
        ax[4] += bf_lo(vx.z); ax[5] += bf_hi(vx.z);
        ax[6] += bf_lo(vx.w); ax[7] += bf_hi(vx.w);
        ae.x += ve.x; ae.y += ve.y; ae.z += ve.z; ae.w += ve.w;
    }
    float4 o0 = make_float4(ax[0] * inv, ax[1] * inv, ax[2] * inv, ax[3] * inv);
    float4 o1 = make_float4(ax[4] * inv, ax[5] * inv, ax[6] * inv, ax[7] * inv);
    A1x[(size_t)node * 16 + s8 * 2 + 0] = o0;
    A1x[(size_t)node * 16 + s8 * 2 + 1] = o1;
    ae.x *= inv; ae.y *= inv; ae.z *= inv; ae.w *= inv;
    A1e[(size_t)node * 8 + s8] = ae;
}

// ---------------------------------------------------------------------------
// Layer-2 aggregate: same structure, 4-way unrolled.
// ---------------------------------------------------------------------------
__global__ __launch_bounds__(256) void agg2_kernel(const uint4* __restrict__ g2b,
                                                   const int2* __restrict__ elist,
                                                   const int* __restrict__ off,
                                                   float4* __restrict__ A2g, int N)
{
    int tid = blockIdx.x * blockDim.x + threadIdx.x;
    int node = tid >> 3;
    int s8 = tid & 7;
    if (node >= N) return;
    int beg = off[node], end = off[node + 1];
    float inv = 1.0f / fmaxf((float)(end - beg), 1.0f);

    float ag[8];
#pragma unroll
    for (int q = 0; q < 8; q++) ag[q] = 0.f;

    int i = beg;
    for (; i + 4 <= end; i += 4) {
        int r0 = elist[i + 0].x;
        int r1 = elist[i + 1].x;
        int r2 = elist[i + 2].x;
        int r3 = elist[i + 3].x;
        uint4 v0 = g2b[(size_t)r0 * 8 + s8];
        uint4 v1 = g2b[(size_t)r1 * 8 + s8];
        uint4 v2 = g2b[(size_t)r2 * 8 + s8];
        uint4 v3 = g2b[(size_t)r3 * 8 + s8];
        ag[0] += (bf_lo(v0.x) + bf_lo(v1.x)) + (bf_lo(v2.x) + bf_lo(v3.x));
        ag[1] += (bf_hi(v0.x) + bf_hi(v1.x)) + (bf_hi(v2.x) + bf_hi(v3.x));
        ag[2] += (bf_lo(v0.y) + bf_lo(v1.y)) + (bf_lo(v2.y) + bf_lo(v3.y));
        ag[3] += (bf_hi(v0.y) + bf_hi(v1.y)) + (bf_hi(v2.y) + bf_hi(v3.y));
        ag[4] += (bf_lo(v0.z) + bf_lo(v1.z)) + (bf_lo(v2.z) + bf_lo(v3.z));
        ag[5] += (bf_hi(v0.z) + bf_hi(v1.z)) + (bf_hi(v2.z) + bf_hi(v3.z));
        ag[6] += (bf_lo(v0.w) + bf_lo(v1.w)) + (bf_lo(v2.w) + bf_lo(v3.w));
        ag[7] += (bf_hi(v0.w) + bf_hi(v1.w)) + (bf_hi(v2.w) + bf_hi(v3.w));
    }
    for (; i < end; i++) {
        int row = elist[i].x;
        uint4 v = g2b[(size_t)row * 8 + s8];
        ag[0] += bf_lo(v.x); ag[1] += bf_hi(v.x);
        ag[2] += bf_lo(v.y); ag[3] += bf_hi(v.y);
        ag[4] += bf_lo(v.z); ag[5] += bf_hi(v.z);
        ag[6] += bf_lo(v.w); ag[7] += bf_hi(v.w);
    }
    float4 o0 = make_float4(ag[0] * inv, ag[1] * inv, ag[2] * inv, ag[3] * inv);
    float4 o1 = make_float4(ag[4] * inv, ag[5] * inv, ag[6] * inv, ag[7] * inv);
    A2g[(size_t)node * 16 + s8 * 2 + 0] = o0;
    A2g[(size_t)node * 16 + s8 * 2 + 1] = o1;
}

// ---------------------------------------------------------------------------
// Layer-1 node kernel (MFMA) — unchanged
// ---------------------------------------------------------------------------
__global__ __launch_bounds__(512) void node1_kernel(
    const uint32* __restrict__ xb,     // [N][32] dwords (bf16x2)
    const float* __restrict__ A1x,     // [N][64] f32
    const float* __restrict__ A1e,     // [N][32] f32
    const int*   __restrict__ deg,
    const ushort16* __restrict__ Wc1T, // [128][160] bf16
    const float* __restrict__ b1eff,
    const float* __restrict__ bmW1,
    const ushort16* __restrict__ Wm2hT,// [64][128] bf16
    uint32* __restrict__ h1b,          // [N][64] dwords (bf16x2)
    uint32* __restrict__ g2b,          // [N][32] dwords (bf16x2)
    int N)
{
    __shared__ ushort16 sFb[NPB][168];  // 160 used, 336B stride
    __shared__ ushort16 sHb[NPB][168];  // 128 used
    __shared__ float sCnt[NPB];

    int t = threadIdx.x;
    int base = blockIdx.x * NPB;
    int tr = t >> 4, c16 = t & 15;
    int v = base + tr;
    bool vok = v < N;

    uint32* sFrow = (uint32*)&sFb[tr][0];
#pragma unroll
    for (int m = 0; m < 5; m++) {
        int d = c16 + 16 * m;
        uint32 w = 0;
        if (vok) {
            if (d < 32) {
                w = xb[(size_t)v * 32 + d];
            } else if (d < 64) {
                int o = (d - 32) * 2;
                w = pack_bf16x2(A1x[(size_t)v * 64 + o], A1x[(size_t)v * 64 + o + 1]);
            } else {
                int o = (d - 64) * 2;
                w = pack_bf16x2(A1e[(size_t)v * 32 + o], A1e[(size_t)v * 32 + o + 1]);
            }
        }
        sFrow[d] = w;
    }
    if (t < NPB) sCnt[t] = (base + t < N) ? (float)deg[base + t] : 1.f;
    __syncthreads();

    int lane = t & 63;
    int wv = t >> 6;
    int lr = lane & 15;
    int kg = lane >> 4;

    f32x4 acc0 = {0.f, 0.f, 0.f, 0.f};
    f32x4 acc1 = {0.f, 0.f, 0.f, 0.f};
    const ushort16* bp1 = &Wc1T[(size_t)(wv * 16 + lr) * 160 + kg * 8];
#pragma unroll
    for (int kt = 0; kt < 5; kt++) {
        bf16x8 a0 = *(const bf16x8*)&sFb[lr][kt * 32 + kg * 8];
        bf16x8 a1 = *(const bf16x8*)&sFb[16 + lr][kt * 32 + kg * 8];
        bf16x8 b  = *(const bf16x8*)&bp1[kt * 32];
        acc0 = MFMA16(a0, b, acc0);
        acc1 = MFMA16(a1, b, acc1);
    }
    int col = wv * 16 + lr;
    float bj = b1eff[col], bw = bmW1[col];
#pragma unroll
    for (int rt = 0; rt < 2; rt++) {
        f32x4 acc = rt ? acc1 : acc0;
        int r0 = rt * 16 + kg * 4;
#pragma unroll
        for (int reg = 0; reg < 4; reg++) {
            float c = sCnt[r0 + reg];
            float hv = fmaxf(acc[reg] + (c > 0.f ? bj : bj - bw), 0.f);
            float other = __shfl_xor(hv, 1);
            if (!(lane & 1))
                ((uint32*)&sHb[r0 + reg][0])[col >> 1] = pack_bf16x2(hv, other);
        }
    }
    __syncthreads();

#pragma unroll
    for (int m = 0; m < 4; m++) {
        int d = c16 + 16 * m;
        if (vok) h1b[(size_t)v * 64 + d] = ((uint32*)&sHb[tr][0])[d];
    }

    int rt2 = wv >> 2, ct2 = wv & 3;
    f32x4 accg = {0.f, 0.f, 0.f, 0.f};
    const ushort16* bp2 = &Wm2hT[(size_t)(ct2 * 16 + lr) * 128 + kg * 8];
#pragma unroll
    for (int kt = 0; kt < 4; kt++) {
        bf16x8 a = *(const bf16x8*)&sHb[rt2 * 16 + lr][kt * 32 + kg * 8];
        bf16x8 b = *(const bf16x8*)&bp2[kt * 32];
        accg = MFMA16(a, b, accg);
    }
    int colg = ct2 * 16 + lr;
    int rg0 = rt2 * 16 + kg * 4;
#pragma unroll
    for (int reg = 0; reg < 4; reg++) {
        float other = __shfl_xor(accg[reg], 1);
        int vr = base + rg0 + reg;
        if (!(lane & 1) && vr < N)
            g2b[(size_t)vr * 32 + (colg >> 1)] = pack_bf16x2(accg[reg], other);
    }
}

// ---------------------------------------------------------------------------
// Layer-2 node kernel (MFMA) — unchanged
// ---------------------------------------------------------------------------
__global__ __launch_bounds__(512) void node2_kernel(
    const uint32* __restrict__ h1b,    // [N][64] dwords
    const float* __restrict__ A2g,     // [N][64] f32
    const float* __restrict__ A1e,     // [N][32] f32
    const int*   __restrict__ deg,
    const ushort16* __restrict__ Wc2T, // [64][224] bf16
    const float* __restrict__ b2eff,
    const float* __restrict__ bmW2,
    float* __restrict__ out,
    int N)
{
    __shared__ ushort16 sFb[NPB][232];  // 224 used, 464B stride
    __shared__ float sCnt[NPB];

    int t = threadIdx.x;
    int base = blockIdx.x * NPB;
    int tr = t >> 4, c16 = t & 15;
    int v = base + tr;
    bool vok = v < N;

    uint32* sFrow = (uint32*)&sFb[tr][0];
#pragma unroll
    for (int m = 0; m < 7; m++) {
        int d = c16 + 16 * m;
        uint32 w = 0;
        if (vok) {
            if (d < 64) {
                w = h1b[(size_t)v * 64 + d];
            } else if (d < 96) {
                int o = (d - 64) * 2;
                w = pack_bf16x2(A2g[(size_t)v * 64 + o], A2g[(size_t)v * 64 + o + 1]);
            } else {
                int o = (d - 96) * 2;
                w = pack_bf16x2(A1e[(size_t)v * 32 + o], A1e[(size_t)v * 32 + o + 1]);
            }
        }
        sFrow[d] = w;
    }
    if (t < NPB) sCnt[t] = (base + t < N) ? (float)deg[base + t] : 1.f;
    __syncthreads();

    int lane = t & 63;
    int wv = t >> 6;
    int lr = lane & 15;
    int kg = lane >> 4;
    int rt = wv >> 2, ct = wv & 3;

    f32x4 acc = {0.f, 0.f, 0.f, 0.f};
    const ushort16* bp = &Wc2T[(size_t)(ct * 16 + lr) * 224 + kg * 8];
#pragma unroll
    for (int kt = 0; kt < 7; kt++) {
        bf16x8 a = *(const bf16x8*)&sFb[rt * 16 + lr][kt * 32 + kg * 8];
        bf16x8 b = *(const bf16x8*)&bp[kt * 32];
        acc = MFMA16(a, b, acc);
    }
    int col = ct * 16 + lr;
    float bj = b2eff[col], bw = bmW2[col];
    int r0 = rt * 16 + kg * 4;
#pragma unroll
    for (int reg = 0; reg < 4; reg++) {
        int vr = base + r0 + reg;
        float c = sCnt[r0 + reg];
        float bias = (c > 0.f) ? bj : bj - bw;
        if (vr < N) out[(size_t)vr * 64 + col] = fmaxf(acc[reg] + bias, 0.f);
    }
}

// ---------------------------------------------------------------------------
extern "C" void kernel_launch(void* const* d_in, const int* in_sizes, int n_in,
                              void* d_out, int out_size, void* d_ws, size_t ws_size,
                              hipStream_t stream) {
    const float* x      = (const float*)d_in[0];
    const int*   ei     = (const int*)d_in[1];
    const float* ea     = (const float*)d_in[2];
    const float* Wmsg1  = (const float*)d_in[3];
    const float* bmsg1  = (const float*)d_in[4];
    const float* Wapp1  = (const float*)d_in[5];
    const float* bapp1  = (const float*)d_in[6];
    const float* Wmsg2  = (const float*)d_in[7];
    const float* bmsg2  = (const float*)d_in[8];
    const float* Wapp2  = (const float*)d_in[9];
    const float* bapp2  = (const float*)d_in[10];

    const int N = in_sizes[0] / 64;      // 50000
    const int E = in_sizes[1] / 2;       // 800000
    const int NCH = (N + SCAN_CHUNK - 1) / SCAN_CHUNK;
    const int* src = ei;
    const int* dst = ei + E;

    uint8_t* p = (uint8_t*)d_ws;
    auto alloc = [&](size_t bytes) -> void* {
        void* r = (void*)p;
        p += (bytes + 255) & ~(size_t)255;
        return r;
    };
    int*     deg    = (int*)alloc((size_t)N * 4);
    int*     off    = (int*)alloc((size_t)(N + 1) * 4);
    int*     cursor = (int*)alloc((size_t)N * 4);
    int*     part   = (int*)alloc((size_t)NCH * 4);
    int2*    elist  = (int2*)alloc((size_t)E * 8);
    float*   A1x    = (float*)alloc((size_t)N * 64 * 4);  // reused as A2g
    float*   A1e    = (float*)alloc((size_t)N * 32 * 4);
    uint32*  xb     = (uint32*)alloc((size_t)N * 32 * 4);
    uint32*  h1b    = (uint32*)alloc((size_t)N * 64 * 4);
    uint32*  g2b    = (uint32*)alloc((size_t)N * 32 * 4);
    ushort16* Wc1T  = (ushort16*)alloc(128 * 160 * 2);
    ushort16* Wc2T  = (ushort16*)alloc(64 * 224 * 2);
    ushort16* Wm2hT = (ushort16*)alloc(64 * 128 * 2);
    float*   b1eff  = (float*)alloc(128 * 4);
    float*   bmW1   = (float*)alloc(128 * 4);
    float*   b2eff  = (float*)alloc(64 * 4);
    float*   bmW2   = (float*)alloc(64 * 4);
    float*   A2g    = A1x;   // safe: A1x consumed by node1 before agg2 writes A2g

    hipMemsetAsync(deg, 0, (size_t)N * 4, stream);

    // Weight composition + x conversion
    compose1_kernel<<<161, 128, 0, stream>>>(Wmsg1, bmsg1, Wapp1, bapp1,
                                             Wc1T, b1eff, bmW1);
    compose2_kernel<<<225, 64, 0, stream>>>(Wmsg2, bmsg2, Wapp2, bapp2,
                                            Wc2T, b2eff, bmW2);
    composem_kernel<<<128, 64, 0, stream>>>(Wmsg2, Wm2hT);
    {
        int n4 = N * 16;
        cvt_x_kernel<<<(n4 + 255) / 256, 256, 0, stream>>>(
            (const float4*)x, (uint2*)xb, n4);
    }

    // CSR build (8 edges/thread)
    {
        int ngroups = (E + 7) / 8;
        hist_kernel<<<(ngroups + 255) / 256, 256, 0, stream>>>(dst, deg, E);
        scanA_kernel<<<NCH, 256, 0, stream>>>(deg, part, N);
        scanB_kernel<<<1, 64, 0, stream>>>(part, off + N, NCH);
        scanC_kernel<<<NCH, SCAN_CHUNK, 0, stream>>>(deg, part, off, cursor, N);
        fill_kernel<<<(ngroups + 255) / 256, 256, 0, stream>>>(src, dst, cursor, elist, E);
    }

    // Layer 1: 8 lanes/node -> 32 nodes per 256-thread block
    agg1_kernel<<<(N + 31) / 32, 256, 0, stream>>>(
        (const uint4*)xb, (const float4*)ea, elist, off,
        (float4*)A1x, (float4*)A1e, N);
    node1_kernel<<<(N + NPB - 1) / NPB, 512, 0, stream>>>(
        xb, A1x, A1e, deg, Wc1T, b1eff, bmW1, Wm2hT, h1b, g2b, N);

    // Layer 2
    agg2_kernel<<<(N + 31) / 32, 256, 0, stream>>>(
        (const uint4*)g2b, elist, off, (float4*)A2g, N);
    node2_kernel<<<(N + NPB - 1) / NPB, 512, 0, stream>>>(
        h1b, A2g, A1e, deg, Wc2T, b2eff, bmW2,
        (float*)d_out, N);
}